// Round 6
// baseline (261.641 us; speedup 1.0000x reference)
//
#include <hip/hip_runtime.h>
#include <hip/hip_bf16.h>
#include <math.h>

#define N_NODES 100000
#define N_EDGES 1600000
#define D_IN 64
#define D_HID 64
#define D_OUT 40
#define NBUCK 256
#define BSZ 391                 // nodes per bucket; 256*391 = 100096 >= N
#define BCAP 10240              // padded csr ints per bucket (mean ~7630, 19+ sd margin)
#define P3_EPB 4096             // edges per k_place block
#define P3_GRID ((N_EDGES + P3_EPB - 1) / P3_EPB)   // 391
#define GEMM_GRID ((N_NODES + 63) / 64)             // 1563 blocks, 16 nodes/wave

typedef __hip_bfloat16 bf16;
typedef __attribute__((ext_vector_type(8))) short short8;
typedef __attribute__((ext_vector_type(4))) float f32x4;

__device__ __forceinline__ float bflo(unsigned int u) {
    union { unsigned int i; float f; } c; c.i = u << 16; return c.f;
}
__device__ __forceinline__ float bfhi(unsigned int u) {
    union { unsigned int i; float f; } c; c.i = u & 0xFFFF0000u; return c.f;
}
// fp32 -> bf16 bits, round-to-nearest-even (finite inputs)
__device__ __forceinline__ unsigned short f2b(float f) {
    union { float f; unsigned int u; } c; c.f = f;
    unsigned int u = c.u + 0x7FFFu + ((c.u >> 16) & 1u);
    return (unsigned short)(u >> 16);
}

// ---- zero ints ----
__global__ __launch_bounds__(256) void k_zero(int* __restrict__ p, int n) {
    int i = blockIdx.x * 256 + threadIdx.x;
    if (i < n) p[i] = 0;
}

// ---- phase 1: global bucket counts (LDS histogram, padded global counters) ----
__global__ __launch_bounds__(256) void k_cnt(const int* __restrict__ col,
                                             int* __restrict__ bcnt_p) {
    __shared__ int hist[NBUCK];
    hist[threadIdx.x] = 0;
    __syncthreads();
    for (int e = blockIdx.x * 256 + threadIdx.x; e < N_EDGES; e += 256 * 256) {
        unsigned int c = (unsigned int)col[e];
        atomicAdd(&hist[c / 391u], 1);
    }
    __syncthreads();
    int hv = hist[threadIdx.x];
    if (hv) atomicAdd(&bcnt_p[threadIdx.x * 16], hv);   // 64B-strided: no line sharing
}

// ---- phase 2: scan 256 bucket counts; init fill = base ----
__global__ __launch_bounds__(256) void k_scan256(const int* __restrict__ bcnt_p,
                                                 int* __restrict__ fill_p,
                                                 int* __restrict__ bucket_base) {
    __shared__ int sm[256];
    int t = threadIdx.x;
    int v = bcnt_p[t * 16];
    sm[t] = v;
    __syncthreads();
    for (int off = 1; off < 256; off <<= 1) {
        int u = (t >= off) ? sm[t - off] : 0;
        __syncthreads();
        sm[t] += u;
        __syncthreads();
    }
    int excl = sm[t] - v;
    bucket_base[t] = excl;
    fill_p[t * 16] = excl;
    if (t == 255) bucket_base[256] = sm[255];
}

// ---- phase 3: partition edges into bucket-contiguous packed array ----
// packed part[] word: (local_c << 17) | src   (9 + 17 = 26 bits)
__global__ __launch_bounds__(256) void k_place(const int* __restrict__ ei,
                                               int* __restrict__ fill_p,
                                               int* __restrict__ part) {
    __shared__ int cnt_l[NBUCK];
    __shared__ int base_l[NBUCK];
    cnt_l[threadIdx.x] = 0;
    __syncthreads();
    int e0 = blockIdx.x * P3_EPB;
    unsigned int meta[16];                     // (b<<21)|(lc<<12)|slot
#pragma unroll
    for (int k = 0; k < 16; k++) {
        int e = e0 + k * 256 + threadIdx.x;
        if (e < N_EDGES) {
            unsigned int c = (unsigned int)ei[N_EDGES + e];
            unsigned int b = c / 391u;
            unsigned int lc = c - b * 391u;
            unsigned int slot = atomicAdd(&cnt_l[b], 1);   // slot < 4096
            meta[k] = (b << 21) | (lc << 12) | slot;
        } else meta[k] = 0xFFFFFFFFu;
    }
    __syncthreads();
    int cv = cnt_l[threadIdx.x];
    if (cv) base_l[threadIdx.x] = atomicAdd(&fill_p[threadIdx.x * 16], cv);
    __syncthreads();
#pragma unroll
    for (int k = 0; k < 16; k++) {
        if (meta[k] != 0xFFFFFFFFu) {
            int e = e0 + k * 256 + threadIdx.x;
            unsigned int b = meta[k] >> 21;
            unsigned int lc = (meta[k] >> 12) & 0x1FFu;
            unsigned int slot = meta[k] & 0xFFFu;
            unsigned int r = (unsigned int)ei[e];
            part[base_l[b] + slot] = (int)((lc << 17) | r);
        }
    }
}

// ---- phase 4: per-bucket PADDED CSR build + start/nkv/dinv ----
// Node lists padded to multiple of 8 with sentinel N_NODES (zero message row).
// Bucket b owns csr[b*BCAP .. (b+1)*BCAP).
__global__ __launch_bounds__(256) void k_build(const int* __restrict__ part,
                                               const int* __restrict__ bucket_base,
                                               int* __restrict__ start,
                                               int* __restrict__ nkv,
                                               float* __restrict__ dinv,
                                               int* __restrict__ csr) {
    __shared__ int deg_l[392];
    __shared__ int excl_l[392];        // exclusive scan of PADDED degrees
    int tid = threadIdx.x;
    int b = blockIdx.x;
    int base = bucket_base[b], end = bucket_base[b + 1];
    int m = end - base;
    int cbase = b * BCAP;
    for (int i = tid; i < 392; i += 256) deg_l[i] = 0;
    __syncthreads();
    for (int i = tid; i < m; i += 256)
        atomicAdd(&deg_l[(unsigned int)part[base + i] >> 17], 1);
    __syncthreads();
    // wave 0: exclusive scan of padded degrees
    if (tid < 64) {
        int carry = 0;
        for (int ch = 0; ch < 7; ch++) {       // 7*64 = 448 >= 392
            int idx = ch * 64 + tid;
            int val = (idx < 392) ? ((deg_l[idx] + 7) & ~7) : 0;
            int incl = val;
#pragma unroll
            for (int off = 1; off < 64; off <<= 1) {
                int u = __shfl_up(incl, off, 64);
                if (tid >= off) incl += u;
            }
            if (idx < 392) excl_l[idx] = carry + incl - val;
            carry += __shfl(incl, 63, 64);
        }
    }
    __syncthreads();
    int v0 = b * BSZ;
    for (int vl = tid; vl < BSZ; vl += 256) {
        int v = v0 + vl;
        if (v < N_NODES) {
            int d = deg_l[vl];
            start[v] = cbase + excl_l[vl];
            nkv[v] = (d + 7) >> 3;
            dinv[v] = rsqrtf((float)d + 1.0f);
        }
    }
    __syncthreads();
    // fill pad slots with zero-row sentinel (uses TRUE deg, before reuse)
    for (int j = tid; j < 392 * 8; j += 256) {
        int vl = j >> 3, sl = j & 7;
        int d = deg_l[vl];
        int pc = ((d + 7) & ~7) - d;           // 0..7 pad slots
        if (sl < pc) csr[cbase + excl_l[vl] + d + sl] = N_NODES;
    }
    __syncthreads();
    for (int i = tid; i < 392; i += 256) deg_l[i] = 0;   // reuse as fill
    __syncthreads();
    for (int i = tid; i < m; i += 256) {
        unsigned int p = (unsigned int)part[base + i];
        unsigned int lc = p >> 17;
        int s = atomicAdd(&deg_l[lc], 1);
        csr[cbase + excl_l[lc] + s] = (int)(p & 0x1FFFFu);
    }
}

// ---- prep: pack W1/W2 into bf16 MFMA A-fragments; zero the sentinel rows ----
__global__ __launch_bounds__(256) void k_prep(const float* __restrict__ W1,
                                              const float* __restrict__ W2,
                                              unsigned short* __restrict__ wp1,
                                              unsigned short* __restrict__ wp2,
                                              unsigned short* __restrict__ gbz,
                                              unsigned short* __restrict__ g2z) {
    int tid = threadIdx.x;
    if (tid < 64) gbz[(size_t)N_NODES * 64 + tid] = 0;          // zero row, layer1
    if (tid >= 64 && tid < 104) g2z[(size_t)N_NODES * 40 + (tid - 64)] = 0;
    for (int i = tid; i < 4096; i += 256) {           // 2 kk * 4 jt * 64 lane * 8 e
        int e = i & 7, lane = (i >> 3) & 63, t = i >> 9;
        int kk = t >> 2, jt = t & 3;
        int row = kk * 32 + (lane >> 4) * 8 + e;
        int col = jt * 16 + (lane & 15);
        wp1[i] = f2b(W1[row * 64 + col]);
    }
    for (int i = tid; i < 3072; i += 256) {           // 2 kk * 3 jt * 64 lane * 8 e
        int e = i & 7, lane = (i >> 3) & 63, t = i >> 9;
        int kk = t / 3, jt = t - kk * 3;
        int row = kk * 32 + (lane >> 4) * 8 + e;
        int col = jt * 16 + (lane & 15);
        wp2[i] = (col < 40) ? f2b(W2[row * 40 + col]) : (unsigned short)0;
    }
}

// ---- layer1 GEMM via MFMA: gb[v][j] = bf16(dinv[v] * (x @ W1)[v][j]) ----
// Wave computes 16 nodes x 64 cols. D = A(W^T) * B(x^T): D col = node, row = j.
__global__ __launch_bounds__(256) void k_gemm1m(const float* __restrict__ x,
                                                const short8* __restrict__ wp,
                                                const float* __restrict__ dinv,
                                                unsigned short* __restrict__ gb) {
    int lane = threadIdx.x & 63;
    int wid = threadIdx.x >> 6;
    int node0 = (blockIdx.x * 4 + wid) * 16;
    if (node0 >= N_NODES) return;
    int vr = node0 + (lane & 15);
    if (vr >= N_NODES) vr = N_NODES - 1;               // defensive (unreachable)
    int kg = lane >> 4;
    const float* px = x + (size_t)vr * 64 + kg * 8;
    short8 b0, b1;
    {
        float4 f0 = *(const float4*)px;
        float4 f1 = *(const float4*)(px + 4);
        b0[0] = (short)f2b(f0.x); b0[1] = (short)f2b(f0.y);
        b0[2] = (short)f2b(f0.z); b0[3] = (short)f2b(f0.w);
        b0[4] = (short)f2b(f1.x); b0[5] = (short)f2b(f1.y);
        b0[6] = (short)f2b(f1.z); b0[7] = (short)f2b(f1.w);
        float4 g0 = *(const float4*)(px + 32);
        float4 g1 = *(const float4*)(px + 36);
        b1[0] = (short)f2b(g0.x); b1[1] = (short)f2b(g0.y);
        b1[2] = (short)f2b(g0.z); b1[3] = (short)f2b(g0.w);
        b1[4] = (short)f2b(g1.x); b1[5] = (short)f2b(g1.y);
        b1[6] = (short)f2b(g1.z); b1[7] = (short)f2b(g1.w);
    }
    f32x4 acc[4];
#pragma unroll
    for (int jt = 0; jt < 4; jt++) acc[jt] = (f32x4){0.f, 0.f, 0.f, 0.f};
#pragma unroll
    for (int jt = 0; jt < 4; jt++) {
        acc[jt] = __builtin_amdgcn_mfma_f32_16x16x32_bf16(
            wp[(0 * 4 + jt) * 64 + lane], b0, acc[jt], 0, 0, 0);
        acc[jt] = __builtin_amdgcn_mfma_f32_16x16x32_bf16(
            wp[(1 * 4 + jt) * 64 + lane], b1, acc[jt], 0, 0, 0);
    }
    float d = dinv[vr];
    unsigned short* gp = gb + (size_t)vr * 64 + kg * 4;
#pragma unroll
    for (int jt = 0; jt < 4; jt++) {
        unsigned int lo = (unsigned int)f2b(acc[jt][0] * d) |
                          ((unsigned int)f2b(acc[jt][1] * d) << 16);
        unsigned int hi = (unsigned int)f2b(acc[jt][2] * d) |
                          ((unsigned int)f2b(acc[jt][3] * d) << 16);
        *(uint2*)(gp + jt * 16) = make_uint2(lo, hi);
    }
}

// ---- layer2 GEMM via MFMA: g2[v][j<40] = bf16(dinv[v] * (h @ W2)[v][j]) ----
// h is bf16 (hb), so B-fragments are direct 16B loads.
__global__ __launch_bounds__(256) void k_gemm2m(const unsigned short* __restrict__ hb,
                                                const short8* __restrict__ wp,
                                                const float* __restrict__ dinv,
                                                unsigned short* __restrict__ g2) {
    int lane = threadIdx.x & 63;
    int wid = threadIdx.x >> 6;
    int node0 = (blockIdx.x * 4 + wid) * 16;
    if (node0 >= N_NODES) return;
    int vr = node0 + (lane & 15);
    if (vr >= N_NODES) vr = N_NODES - 1;
    int kg = lane >> 4;
    const short8* h8 = (const short8*)hb;
    short8 b0 = h8[(size_t)vr * 8 + kg];
    short8 b1 = h8[(size_t)vr * 8 + 4 + kg];
    f32x4 acc[3];
#pragma unroll
    for (int jt = 0; jt < 3; jt++) acc[jt] = (f32x4){0.f, 0.f, 0.f, 0.f};
#pragma unroll
    for (int jt = 0; jt < 3; jt++) {
        acc[jt] = __builtin_amdgcn_mfma_f32_16x16x32_bf16(
            wp[(0 * 3 + jt) * 64 + lane], b0, acc[jt], 0, 0, 0);
        acc[jt] = __builtin_amdgcn_mfma_f32_16x16x32_bf16(
            wp[(1 * 3 + jt) * 64 + lane], b1, acc[jt], 0, 0, 0);
    }
    float d = dinv[vr];
    unsigned short* gp = g2 + (size_t)vr * 40 + kg * 4;
#pragma unroll
    for (int jt = 0; jt < 3; jt++) {
        if (jt == 2 && kg >= 2) break;                 // j >= 40
        unsigned int lo = (unsigned int)f2b(acc[jt][0] * d) |
                          ((unsigned int)f2b(acc[jt][1] * d) << 16);
        unsigned int hi = (unsigned int)f2b(acc[jt][2] * d) |
                          ((unsigned int)f2b(acc[jt][3] * d) << 16);
        *(uint2*)(gp + jt * 16) = make_uint2(lo, hi);
    }
}

// ---- agg1: 8-lane edge-groups, uint4 (8xbf16) gathers. ZERO-PADDED csr:
//      no predication at all, exact trip count; bias + ReLU -> hb (bf16) ----
__global__ __launch_bounds__(256) void k_agg1(const int* __restrict__ csr,
                                              const int* __restrict__ start,
                                              const int* __restrict__ nkv,
                                              const unsigned int* __restrict__ gb2,
                                              const float* __restrict__ dinv,
                                              const float* __restrict__ b1,
                                              unsigned short* __restrict__ hb) {
    int lane = threadIdx.x & 63;
    int g = lane >> 3;          // 8 edge-groups of 8 lanes; group g -> edges 8*k+g
    int lq = lane & 7;          // 16B slice lq of the 128B row (cols 8lq..8lq+7)
    int v = blockIdx.x * 4 + (threadIdx.x >> 6);
    int s = start[v] + g;
    int nk = nkv[v];
    float a0=0.f,a1=0.f,a2=0.f,a3=0.f,a4=0.f,a5=0.f,a6=0.f,a7=0.f;
    if (g == 0) {               // self-loop contribution
        uint4 u = *(const uint4*)(gb2 + (size_t)v * 32 + lq * 4);
        a0 += bflo(u.x); a1 += bfhi(u.x); a2 += bflo(u.y); a3 += bfhi(u.y);
        a4 += bflo(u.z); a5 += bfhi(u.z); a6 += bflo(u.w); a7 += bfhi(u.w);
    }
#pragma unroll 2
    for (int k = 0; k < nk; k++) {
        int r = csr[s + k * 8];                        // pad edges -> zero row
        uint4 u = *(const uint4*)(gb2 + (size_t)r * 32 + lq * 4);
        a0 += bflo(u.x); a1 += bfhi(u.x); a2 += bflo(u.y); a3 += bfhi(u.y);
        a4 += bflo(u.z); a5 += bfhi(u.z); a6 += bflo(u.w); a7 += bfhi(u.w);
    }
    // fold the 8 edge-groups (all 64 lanes active at every shfl)
#pragma unroll
    for (int o = 8; o < 64; o <<= 1) {
        a0 += __shfl_xor(a0, o, 64); a1 += __shfl_xor(a1, o, 64);
        a2 += __shfl_xor(a2, o, 64); a3 += __shfl_xor(a3, o, 64);
        a4 += __shfl_xor(a4, o, 64); a5 += __shfl_xor(a5, o, 64);
        a6 += __shfl_xor(a6, o, 64); a7 += __shfl_xor(a7, o, 64);
    }
    float d = dinv[v];
    float4 bb0 = ((const float4*)b1)[lq * 2];
    float4 bb1 = ((const float4*)b1)[lq * 2 + 1];
    float h0 = fmaxf(d * a0 + bb0.x, 0.f), h1 = fmaxf(d * a1 + bb0.y, 0.f);
    float h2 = fmaxf(d * a2 + bb0.z, 0.f), h3 = fmaxf(d * a3 + bb0.w, 0.f);
    float h4 = fmaxf(d * a4 + bb1.x, 0.f), h5 = fmaxf(d * a5 + bb1.y, 0.f);
    float h6 = fmaxf(d * a6 + bb1.z, 0.f), h7 = fmaxf(d * a7 + bb1.w, 0.f);
    if (g == 0) {
        uint4 o;
        o.x = (unsigned int)f2b(h0) | ((unsigned int)f2b(h1) << 16);
        o.y = (unsigned int)f2b(h2) | ((unsigned int)f2b(h3) << 16);
        o.z = (unsigned int)f2b(h4) | ((unsigned int)f2b(h5) << 16);
        o.w = (unsigned int)f2b(h6) | ((unsigned int)f2b(h7) << 16);
        *(uint4*)(hb + (size_t)v * 64 + lq * 8) = o;
    }
}

// ---- agg2: 8-lane edge-groups (5 active slices: 5x16B = 80B row). ZERO-PADDED
//      csr, no predication in loop (idle-lane garbage masked in epilogue);
//      fused bias + log_softmax -> out ----
__global__ __launch_bounds__(256) void k_agg2(const int* __restrict__ csr,
                                              const int* __restrict__ start,
                                              const int* __restrict__ nkv,
                                              const unsigned int* __restrict__ g2b2,
                                              const float* __restrict__ dinv,
                                              const float* __restrict__ b2v,
                                              float* __restrict__ out) {
    int lane = threadIdx.x & 63;
    int g = lane >> 3;          // 8 edge-groups of 8 lanes
    int lq = lane & 7;          // 16B slice of the 80B row; active lq<5
    int v = blockIdx.x * 4 + (threadIdx.x >> 6);
    int s = start[v] + g;
    int nk = nkv[v];
    bool act = (lq < 5);
    int lqc = act ? lq : 0;     // idle lanes alias slice 0 (same line, dedup'd)
    float a0=0.f,a1=0.f,a2=0.f,a3=0.f,a4=0.f,a5=0.f,a6=0.f,a7=0.f;
    if (g == 0 && act) {        // self-loop contribution
        uint4 u = *(const uint4*)(g2b2 + (size_t)v * 20 + lq * 4);
        a0 += bflo(u.x); a1 += bfhi(u.x); a2 += bflo(u.y); a3 += bfhi(u.y);
        a4 += bflo(u.z); a5 += bfhi(u.z); a6 += bflo(u.w); a7 += bfhi(u.w);
    }
#pragma unroll 2
    for (int k = 0; k < nk; k++) {
        int r = csr[s + k * 8];                        // pad edges -> zero row
        uint4 u = *(const uint4*)(g2b2 + (size_t)r * 20 + lqc * 4);
        a0 += bflo(u.x); a1 += bfhi(u.x); a2 += bflo(u.y); a3 += bfhi(u.y);
        a4 += bflo(u.z); a5 += bfhi(u.z); a6 += bflo(u.w); a7 += bfhi(u.w);
    }
    // fold the 8 edge-groups (same-lq lanes only; idle-lane garbage stays idle)
#pragma unroll
    for (int o = 8; o < 64; o <<= 1) {
        a0 += __shfl_xor(a0, o, 64); a1 += __shfl_xor(a1, o, 64);
        a2 += __shfl_xor(a2, o, 64); a3 += __shfl_xor(a3, o, 64);
        a4 += __shfl_xor(a4, o, 64); a5 += __shfl_xor(a5, o, 64);
        a6 += __shfl_xor(a6, o, 64); a7 += __shfl_xor(a7, o, 64);
    }
    float d = dinv[v];
    float4 bb0 = act ? ((const float4*)b2v)[lq * 2] : make_float4(0.f,0.f,0.f,0.f);
    float4 bb1 = act ? ((const float4*)b2v)[lq * 2 + 1] : make_float4(0.f,0.f,0.f,0.f);
    float l0 = act ? d * a0 + bb0.x : -INFINITY;
    float l1 = act ? d * a1 + bb0.y : -INFINITY;
    float l2 = act ? d * a2 + bb0.z : -INFINITY;
    float l3 = act ? d * a3 + bb0.w : -INFINITY;
    float l4 = act ? d * a4 + bb1.x : -INFINITY;
    float l5 = act ? d * a5 + bb1.y : -INFINITY;
    float l6 = act ? d * a6 + bb1.z : -INFINITY;
    float l7 = act ? d * a7 + bb1.w : -INFINITY;
    float m = fmaxf(fmaxf(fmaxf(l0, l1), fmaxf(l2, l3)),
                    fmaxf(fmaxf(l4, l5), fmaxf(l6, l7)));
#pragma unroll
    for (int o = 1; o < 8; o <<= 1) m = fmaxf(m, __shfl_xor(m, o, 64));
    float ex = act ? (__expf(l0 - m) + __expf(l1 - m) + __expf(l2 - m) +
                      __expf(l3 - m) + __expf(l4 - m) + __expf(l5 - m) +
                      __expf(l6 - m) + __expf(l7 - m)) : 0.f;
#pragma unroll
    for (int o = 1; o < 8; o <<= 1) ex += __shfl_xor(ex, o, 64);
    float lse = m + logf(ex);
    if (g == 0 && act) {
        float* op = out + (size_t)v * 40 + lq * 8;
        *(float4*)op = make_float4(l0 - lse, l1 - lse, l2 - lse, l3 - lse);
        *(float4*)(op + 4) = make_float4(l4 - lse, l5 - lse, l6 - lse, l7 - lse);
    }
}

extern "C" void kernel_launch(void* const* d_in, const int* in_sizes, int n_in,
                              void* d_out, int out_size, void* d_ws, size_t ws_size,
                              hipStream_t stream) {
    const float* x  = (const float*)d_in[0];
    const int*   ei = (const int*)d_in[1];
    const float* W1 = (const float*)d_in[2];
    const float* b1 = (const float*)d_in[3];
    const float* W2 = (const float*)d_in[4];
    const float* b2 = (const float*)d_in[5];
    float* out = (float*)d_out;

    const int N = N_NODES;
    // Workspace layout (ints from base), total ~51.7 MB:
    int*   part  = (int*)d_ws;                  // E packed partitioned edges
    int*   csr   = part + N_EDGES;              // 256*BCAP padded CSR
    int*   start = csr + NBUCK * BCAP;          // N
    int*   nkv   = start + N;                   // N  (padded deg / 8)
    int*   bcnt  = nkv + N;                     // 256*16 padded counters
    int*   fill  = bcnt + 4096;                 // 256*16 padded counters
    int*   bbase = fill + 4096;                 // 257 (+pad -> 260)
    float* dinv  = (float*)(bbase + 260);       // N (16B-aligned)
    unsigned short* hb  = (unsigned short*)(dinv + N);   // N*64 bf16
    unsigned short* gb  = hb + (size_t)N * 64;           // (N+1)*64 bf16 (+zero row)
    unsigned short* g2  = gb + (size_t)(N + 1) * 64;     // (N+1)*40 bf16 (+zero row)
    unsigned short* wp1 = g2 + (size_t)(N + 1) * 40;     // 4096 bf16 W1 fragments
    unsigned short* wp2 = wp1 + 4096;                    // 3072 bf16 W2 fragments

    k_zero<<<16, 256, 0, stream>>>(bcnt, 4096);
    k_prep<<<1, 256, 0, stream>>>(W1, W2, wp1, wp2, gb, g2);
    k_cnt<<<256, 256, 0, stream>>>(ei + N_EDGES, bcnt);
    k_scan256<<<1, 256, 0, stream>>>(bcnt, fill, bbase);
    k_place<<<P3_GRID, 256, 0, stream>>>(ei, fill, part);
    k_build<<<NBUCK, 256, 0, stream>>>(part, bbase, start, nkv, dinv, csr);
    k_gemm1m<<<GEMM_GRID, 256, 0, stream>>>(x, (const short8*)wp1, dinv, gb);
    k_agg1<<<N / 4, 256, 0, stream>>>(csr, start, nkv, (const unsigned int*)gb,
                                      dinv, b1, hb);
    k_gemm2m<<<GEMM_GRID, 256, 0, stream>>>(hb, (const short8*)wp2, dinv, g2);
    k_agg2<<<N / 4, 256, 0, stream>>>(csr, start, nkv, (const unsigned int*)g2,
                                      dinv, b2, out);
}

// Round 7
// 254.258 us; speedup vs baseline: 1.0290x; 1.0290x over previous
//
#include <hip/hip_runtime.h>
#include <hip/hip_bf16.h>
#include <math.h>

#define N_NODES 100000
#define N_EDGES 1600000
#define D_IN 64
#define D_HID 64
#define D_OUT 40
#define NBUCK 256
#define BSZ 391                 // nodes per bucket; 256*391 = 100096 >= N
#define BCAP 10240              // padded csr ints per bucket (mean ~7630, 19+ sd margin)
#define P3_EPB 4096             // edges per k_place block
#define P3_GRID ((N_EDGES + P3_EPB - 1) / P3_EPB)   // 391
#define GEMM_GRID ((N_NODES + 63) / 64)             // 1563 blocks, 16 nodes/wave

typedef __hip_bfloat16 bf16;
typedef __attribute__((ext_vector_type(8))) short short8;
typedef __attribute__((ext_vector_type(4))) float f32x4;

__device__ __forceinline__ float bflo(unsigned int u) {
    union { unsigned int i; float f; } c; c.i = u << 16; return c.f;
}
__device__ __forceinline__ float bfhi(unsigned int u) {
    union { unsigned int i; float f; } c; c.i = u & 0xFFFF0000u; return c.f;
}
// fp32 -> bf16 bits, round-to-nearest-even (finite inputs)
__device__ __forceinline__ unsigned short f2b(float f) {
    union { float f; unsigned int u; } c; c.f = f;
    unsigned int u = c.u + 0x7FFFu + ((c.u >> 16) & 1u);
    return (unsigned short)(u >> 16);
}
// signed byte b (0..3) of word w -> float
__device__ __forceinline__ float i8f(unsigned int w, int b) {
    return (float)((int)(w << ((3 - b) * 8)) >> 24);
}
// pack 4 quantized floats into a word
__device__ __forceinline__ unsigned int qpack(float v0, float v1, float v2,
                                              float v3, float qs) {
    int q0 = __float2int_rn(v0 * qs), q1 = __float2int_rn(v1 * qs);
    int q2 = __float2int_rn(v2 * qs), q3 = __float2int_rn(v3 * qs);
    return (unsigned int)(q0 & 255) | ((unsigned int)(q1 & 255) << 8) |
           ((unsigned int)(q2 & 255) << 16) | ((unsigned int)(q3 & 255) << 24);
}

// ---- zero ints ----
__global__ __launch_bounds__(256) void k_zero(int* __restrict__ p, int n) {
    int i = blockIdx.x * 256 + threadIdx.x;
    if (i < n) p[i] = 0;
}

// ---- phase 1: global bucket counts (LDS histogram, padded global counters) ----
__global__ __launch_bounds__(256) void k_cnt(const int* __restrict__ col,
                                             int* __restrict__ bcnt_p) {
    __shared__ int hist[NBUCK];
    hist[threadIdx.x] = 0;
    __syncthreads();
    for (int e = blockIdx.x * 256 + threadIdx.x; e < N_EDGES; e += 256 * 256) {
        unsigned int c = (unsigned int)col[e];
        atomicAdd(&hist[c / 391u], 1);
    }
    __syncthreads();
    int hv = hist[threadIdx.x];
    if (hv) atomicAdd(&bcnt_p[threadIdx.x * 16], hv);   // 64B-strided: no line sharing
}

// ---- phase 2: scan 256 bucket counts; init fill = base ----
__global__ __launch_bounds__(256) void k_scan256(const int* __restrict__ bcnt_p,
                                                 int* __restrict__ fill_p,
                                                 int* __restrict__ bucket_base) {
    __shared__ int sm[256];
    int t = threadIdx.x;
    int v = bcnt_p[t * 16];
    sm[t] = v;
    __syncthreads();
    for (int off = 1; off < 256; off <<= 1) {
        int u = (t >= off) ? sm[t - off] : 0;
        __syncthreads();
        sm[t] += u;
        __syncthreads();
    }
    int excl = sm[t] - v;
    bucket_base[t] = excl;
    fill_p[t * 16] = excl;
    if (t == 255) bucket_base[256] = sm[255];
}

// ---- phase 3: partition edges into bucket-contiguous packed array ----
// packed part[] word: (local_c << 17) | src   (9 + 17 = 26 bits)
__global__ __launch_bounds__(256) void k_place(const int* __restrict__ ei,
                                               int* __restrict__ fill_p,
                                               int* __restrict__ part) {
    __shared__ int cnt_l[NBUCK];
    __shared__ int base_l[NBUCK];
    cnt_l[threadIdx.x] = 0;
    __syncthreads();
    int e0 = blockIdx.x * P3_EPB;
    unsigned int meta[16];                     // (b<<21)|(lc<<12)|slot
#pragma unroll
    for (int k = 0; k < 16; k++) {
        int e = e0 + k * 256 + threadIdx.x;
        if (e < N_EDGES) {
            unsigned int c = (unsigned int)ei[N_EDGES + e];
            unsigned int b = c / 391u;
            unsigned int lc = c - b * 391u;
            unsigned int slot = atomicAdd(&cnt_l[b], 1);   // slot < 4096
            meta[k] = (b << 21) | (lc << 12) | slot;
        } else meta[k] = 0xFFFFFFFFu;
    }
    __syncthreads();
    int cv = cnt_l[threadIdx.x];
    if (cv) base_l[threadIdx.x] = atomicAdd(&fill_p[threadIdx.x * 16], cv);
    __syncthreads();
#pragma unroll
    for (int k = 0; k < 16; k++) {
        if (meta[k] != 0xFFFFFFFFu) {
            int e = e0 + k * 256 + threadIdx.x;
            unsigned int b = meta[k] >> 21;
            unsigned int lc = (meta[k] >> 12) & 0x1FFu;
            unsigned int slot = meta[k] & 0xFFFu;
            unsigned int r = (unsigned int)ei[e];
            part[base_l[b] + slot] = (int)((lc << 17) | r);
        }
    }
}

// ---- phase 4: per-bucket PADDED CSR build + start/nkv/dinv ----
// Node lists padded to multiple of 8 with sentinel N_NODES (zero message row).
// Bucket b owns csr[b*BCAP .. (b+1)*BCAP).
__global__ __launch_bounds__(256) void k_build(const int* __restrict__ part,
                                               const int* __restrict__ bucket_base,
                                               int* __restrict__ start,
                                               int* __restrict__ nkv,
                                               float* __restrict__ dinv,
                                               int* __restrict__ csr) {
    __shared__ int deg_l[392];
    __shared__ int excl_l[392];        // exclusive scan of PADDED degrees
    int tid = threadIdx.x;
    int b = blockIdx.x;
    int base = bucket_base[b], end = bucket_base[b + 1];
    int m = end - base;
    int cbase = b * BCAP;
    for (int i = tid; i < 392; i += 256) deg_l[i] = 0;
    __syncthreads();
    for (int i = tid; i < m; i += 256)
        atomicAdd(&deg_l[(unsigned int)part[base + i] >> 17], 1);
    __syncthreads();
    // wave 0: exclusive scan of padded degrees
    if (tid < 64) {
        int carry = 0;
        for (int ch = 0; ch < 7; ch++) {       // 7*64 = 448 >= 392
            int idx = ch * 64 + tid;
            int val = (idx < 392) ? ((deg_l[idx] + 7) & ~7) : 0;
            int incl = val;
#pragma unroll
            for (int off = 1; off < 64; off <<= 1) {
                int u = __shfl_up(incl, off, 64);
                if (tid >= off) incl += u;
            }
            if (idx < 392) excl_l[idx] = carry + incl - val;
            carry += __shfl(incl, 63, 64);
        }
    }
    __syncthreads();
    int v0 = b * BSZ;
    for (int vl = tid; vl < BSZ; vl += 256) {
        int v = v0 + vl;
        if (v < N_NODES) {
            int d = deg_l[vl];
            start[v] = cbase + excl_l[vl];
            nkv[v] = (d + 7) >> 3;
            dinv[v] = rsqrtf((float)d + 1.0f);
        }
    }
    __syncthreads();
    // fill pad slots with zero-row sentinel (uses TRUE deg, before reuse)
    for (int j = tid; j < 392 * 8; j += 256) {
        int vl = j >> 3, sl = j & 7;
        int d = deg_l[vl];
        int pc = ((d + 7) & ~7) - d;           // 0..7 pad slots
        if (sl < pc) csr[cbase + excl_l[vl] + d + sl] = N_NODES;
    }
    __syncthreads();
    for (int i = tid; i < 392; i += 256) deg_l[i] = 0;   // reuse as fill
    __syncthreads();
    for (int i = tid; i < m; i += 256) {
        unsigned int p = (unsigned int)part[base + i];
        unsigned int lc = p >> 17;
        int s = atomicAdd(&deg_l[lc], 1);
        csr[cbase + excl_l[lc] + s] = (int)(p & 0x1FFFFu);
    }
}

// ---- prep: pack W1/W2 into bf16 MFMA A-fragments; zero sentinel q-rows ----
__global__ __launch_bounds__(256) void k_prep(const float* __restrict__ W1,
                                              const float* __restrict__ W2,
                                              unsigned short* __restrict__ wp1,
                                              unsigned short* __restrict__ wp2,
                                              unsigned int* __restrict__ gb8,
                                              unsigned int* __restrict__ g2q,
                                              float* __restrict__ scale1,
                                              float* __restrict__ scale2) {
    int tid = threadIdx.x;
    if (tid < 16) gb8[(size_t)N_NODES * 16 + tid] = 0;   // sentinel zero rows
    else if (tid < 32) g2q[(size_t)N_NODES * 16 + (tid - 16)] = 0;
    else if (tid == 32) { scale1[N_NODES] = 0.f; scale2[N_NODES] = 0.f; }
    for (int i = tid; i < 4096; i += 256) {           // 2 kk * 4 jt * 64 lane * 8 e
        int e = i & 7, lane = (i >> 3) & 63, t = i >> 9;
        int kk = t >> 2, jt = t & 3;
        int row = kk * 32 + (lane >> 4) * 8 + e;
        int col = jt * 16 + (lane & 15);
        wp1[i] = f2b(W1[row * 64 + col]);
    }
    for (int i = tid; i < 3072; i += 256) {           // 2 kk * 3 jt * 64 lane * 8 e
        int e = i & 7, lane = (i >> 3) & 63, t = i >> 9;
        int kk = t / 3, jt = t - kk * 3;
        int row = kk * 32 + (lane >> 4) * 8 + e;
        int col = jt * 16 + (lane & 15);
        wp2[i] = (col < 40) ? f2b(W2[row * 40 + col]) : (unsigned short)0;
    }
}

// ---- layer1 GEMM via MFMA, int8 row-quantized output ----
// gb8 row v: 64 bytes = cols 0..63 int8; scale1[v] = row amax / 127.
__global__ __launch_bounds__(256) void k_gemm1m(const float* __restrict__ x,
                                                const short8* __restrict__ wp,
                                                const float* __restrict__ dinv,
                                                unsigned int* __restrict__ gb8,
                                                float* __restrict__ scale1) {
    int lane = threadIdx.x & 63;
    int wid = threadIdx.x >> 6;
    int node0 = (blockIdx.x * 4 + wid) * 16;
    if (node0 >= N_NODES) return;
    int vr = node0 + (lane & 15);
    if (vr >= N_NODES) vr = N_NODES - 1;               // defensive (unreachable)
    int kg = lane >> 4;
    const float* px = x + (size_t)vr * 64 + kg * 8;
    short8 b0, b1;
    {
        float4 f0 = *(const float4*)px;
        float4 f1 = *(const float4*)(px + 4);
        b0[0] = (short)f2b(f0.x); b0[1] = (short)f2b(f0.y);
        b0[2] = (short)f2b(f0.z); b0[3] = (short)f2b(f0.w);
        b0[4] = (short)f2b(f1.x); b0[5] = (short)f2b(f1.y);
        b0[6] = (short)f2b(f1.z); b0[7] = (short)f2b(f1.w);
        float4 g0 = *(const float4*)(px + 32);
        float4 g1 = *(const float4*)(px + 36);
        b1[0] = (short)f2b(g0.x); b1[1] = (short)f2b(g0.y);
        b1[2] = (short)f2b(g0.z); b1[3] = (short)f2b(g0.w);
        b1[4] = (short)f2b(g1.x); b1[5] = (short)f2b(g1.y);
        b1[6] = (short)f2b(g1.z); b1[7] = (short)f2b(g1.w);
    }
    f32x4 acc[4];
#pragma unroll
    for (int jt = 0; jt < 4; jt++) acc[jt] = (f32x4){0.f, 0.f, 0.f, 0.f};
#pragma unroll
    for (int jt = 0; jt < 4; jt++) {
        acc[jt] = __builtin_amdgcn_mfma_f32_16x16x32_bf16(
            wp[(0 * 4 + jt) * 64 + lane], b0, acc[jt], 0, 0, 0);
        acc[jt] = __builtin_amdgcn_mfma_f32_16x16x32_bf16(
            wp[(1 * 4 + jt) * 64 + lane], b1, acc[jt], 0, 0, 0);
    }
    float d = dinv[vr];
    float mv[4][4];
    float amax = 0.f;
#pragma unroll
    for (int jt = 0; jt < 4; jt++)
#pragma unroll
        for (int i = 0; i < 4; i++) {
            float val = acc[jt][i] * d;
            mv[jt][i] = val;
            amax = fmaxf(amax, fabsf(val));
        }
    amax = fmaxf(amax, __shfl_xor(amax, 16, 64));
    amax = fmaxf(amax, __shfl_xor(amax, 32, 64));
    float qs = (amax > 0.f) ? 127.f / amax : 0.f;
    if (kg == 0) scale1[vr] = amax * (1.f / 127.f);
    unsigned int* gp = gb8 + (size_t)vr * 16 + kg;
#pragma unroll
    for (int jt = 0; jt < 4; jt++)
        gp[jt * 4] = qpack(mv[jt][0], mv[jt][1], mv[jt][2], mv[jt][3], qs);
}

// ---- layer2 GEMM via MFMA, int8 row-quantized output (40 cols + zero pad) ----
// g2q row v: 64 bytes, cols 0..39 int8, bytes 40..63 zero; scale2[v].
__global__ __launch_bounds__(256) void k_gemm2m(const unsigned short* __restrict__ hb,
                                                const short8* __restrict__ wp,
                                                const float* __restrict__ dinv,
                                                unsigned int* __restrict__ g2q,
                                                float* __restrict__ scale2) {
    int lane = threadIdx.x & 63;
    int wid = threadIdx.x >> 6;
    int node0 = (blockIdx.x * 4 + wid) * 16;
    if (node0 >= N_NODES) return;
    int vr = node0 + (lane & 15);
    if (vr >= N_NODES) vr = N_NODES - 1;
    int kg = lane >> 4;
    const short8* h8 = (const short8*)hb;
    short8 b0 = h8[(size_t)vr * 8 + kg];
    short8 b1 = h8[(size_t)vr * 8 + 4 + kg];
    f32x4 acc[3];
#pragma unroll
    for (int jt = 0; jt < 3; jt++) acc[jt] = (f32x4){0.f, 0.f, 0.f, 0.f};
#pragma unroll
    for (int jt = 0; jt < 3; jt++) {
        acc[jt] = __builtin_amdgcn_mfma_f32_16x16x32_bf16(
            wp[(0 * 3 + jt) * 64 + lane], b0, acc[jt], 0, 0, 0);
        acc[jt] = __builtin_amdgcn_mfma_f32_16x16x32_bf16(
            wp[(1 * 3 + jt) * 64 + lane], b1, acc[jt], 0, 0, 0);
    }
    float d = dinv[vr];
    bool v2 = (kg < 2);                                // jt=2 valid only kg<2
    float mv[3][4];
    float amax = 0.f;
#pragma unroll
    for (int jt = 0; jt < 3; jt++)
#pragma unroll
        for (int i = 0; i < 4; i++) {
            float val = acc[jt][i] * d;
            mv[jt][i] = val;
            if (jt < 2 || v2) amax = fmaxf(amax, fabsf(val));
        }
    amax = fmaxf(amax, __shfl_xor(amax, 16, 64));
    amax = fmaxf(amax, __shfl_xor(amax, 32, 64));
    float qs = (amax > 0.f) ? 127.f / amax : 0.f;
    if (kg == 0) scale2[vr] = amax * (1.f / 127.f);
    unsigned int* gp = g2q + (size_t)vr * 16;
    gp[0 * 4 + kg] = qpack(mv[0][0], mv[0][1], mv[0][2], mv[0][3], qs);
    gp[1 * 4 + kg] = qpack(mv[1][0], mv[1][1], mv[1][2], mv[1][3], qs);
    gp[8 + kg] = v2 ? qpack(mv[2][0], mv[2][1], mv[2][2], mv[2][3], qs) : 0u;
    gp[12 + kg] = 0u;                                  // pad bytes 48..63
}

// ---- agg1: 8-lane edge-groups, int8 rows (64B = 1 line), per-row scale;
//      zero-padded csr, no predication; bias + ReLU -> hb (bf16) ----
__global__ __launch_bounds__(256) void k_agg1(const int* __restrict__ csr,
                                              const int* __restrict__ start,
                                              const int* __restrict__ nkv,
                                              const unsigned int* __restrict__ gb8,
                                              const float* __restrict__ scale1,
                                              const float* __restrict__ dinv,
                                              const float* __restrict__ b1,
                                              unsigned short* __restrict__ hb) {
    int lane = threadIdx.x & 63;
    int g = lane >> 3;          // 8 edge-groups of 8 lanes; group g -> edges 8*k+g
    int lq = lane & 7;          // 8B slice lq (cols 8lq..8lq+7)
    int v = blockIdx.x * 4 + (threadIdx.x >> 6);
    int s = start[v] + g;
    int nk = nkv[v];
    float a0=0.f,a1=0.f,a2=0.f,a3=0.f,a4=0.f,a5=0.f,a6=0.f,a7=0.f;
    if (g == 0) {               // self-loop contribution
        float sc = scale1[v];
        uint2 u = *(const uint2*)(gb8 + (size_t)v * 16 + lq * 2);
        a0 = fmaf(i8f(u.x,0), sc, a0); a1 = fmaf(i8f(u.x,1), sc, a1);
        a2 = fmaf(i8f(u.x,2), sc, a2); a3 = fmaf(i8f(u.x,3), sc, a3);
        a4 = fmaf(i8f(u.y,0), sc, a4); a5 = fmaf(i8f(u.y,1), sc, a5);
        a6 = fmaf(i8f(u.y,2), sc, a6); a7 = fmaf(i8f(u.y,3), sc, a7);
    }
#pragma unroll 2
    for (int k = 0; k < nk; k++) {
        int r = csr[s + k * 8];                        // pad edges -> zero row
        float sc = scale1[r];
        uint2 u = *(const uint2*)(gb8 + (size_t)r * 16 + lq * 2);
        a0 = fmaf(i8f(u.x,0), sc, a0); a1 = fmaf(i8f(u.x,1), sc, a1);
        a2 = fmaf(i8f(u.x,2), sc, a2); a3 = fmaf(i8f(u.x,3), sc, a3);
        a4 = fmaf(i8f(u.y,0), sc, a4); a5 = fmaf(i8f(u.y,1), sc, a5);
        a6 = fmaf(i8f(u.y,2), sc, a6); a7 = fmaf(i8f(u.y,3), sc, a7);
    }
    // fold the 8 edge-groups (all 64 lanes active at every shfl)
#pragma unroll
    for (int o = 8; o < 64; o <<= 1) {
        a0 += __shfl_xor(a0, o, 64); a1 += __shfl_xor(a1, o, 64);
        a2 += __shfl_xor(a2, o, 64); a3 += __shfl_xor(a3, o, 64);
        a4 += __shfl_xor(a4, o, 64); a5 += __shfl_xor(a5, o, 64);
        a6 += __shfl_xor(a6, o, 64); a7 += __shfl_xor(a7, o, 64);
    }
    float d = dinv[v];
    float4 bb0 = ((const float4*)b1)[lq * 2];
    float4 bb1 = ((const float4*)b1)[lq * 2 + 1];
    float h0 = fmaxf(d * a0 + bb0.x, 0.f), h1 = fmaxf(d * a1 + bb0.y, 0.f);
    float h2 = fmaxf(d * a2 + bb0.z, 0.f), h3 = fmaxf(d * a3 + bb0.w, 0.f);
    float h4 = fmaxf(d * a4 + bb1.x, 0.f), h5 = fmaxf(d * a5 + bb1.y, 0.f);
    float h6 = fmaxf(d * a6 + bb1.z, 0.f), h7 = fmaxf(d * a7 + bb1.w, 0.f);
    if (g == 0) {
        uint4 o;
        o.x = (unsigned int)f2b(h0) | ((unsigned int)f2b(h1) << 16);
        o.y = (unsigned int)f2b(h2) | ((unsigned int)f2b(h3) << 16);
        o.z = (unsigned int)f2b(h4) | ((unsigned int)f2b(h5) << 16);
        o.w = (unsigned int)f2b(h6) | ((unsigned int)f2b(h7) << 16);
        *(uint4*)(hb + (size_t)v * 64 + lq * 8) = o;
    }
}

// ---- agg2: 8-lane edge-groups, int8 rows (64B = 1 line: 40 cols + zero pad),
//      per-row scale; zero-padded csr; fused bias + log_softmax -> out ----
__global__ __launch_bounds__(256) void k_agg2(const int* __restrict__ csr,
                                              const int* __restrict__ start,
                                              const int* __restrict__ nkv,
                                              const unsigned int* __restrict__ g2q,
                                              const float* __restrict__ scale2,
                                              const float* __restrict__ dinv,
                                              const float* __restrict__ b2v,
                                              float* __restrict__ out) {
    int lane = threadIdx.x & 63;
    int g = lane >> 3;          // 8 edge-groups of 8 lanes
    int lq = lane & 7;          // 8B slice (cols 8lq..); active lq<5
    int v = blockIdx.x * 4 + (threadIdx.x >> 6);
    int s = start[v] + g;
    int nk = nkv[v];
    bool act = (lq < 5);
    float a0=0.f,a1=0.f,a2=0.f,a3=0.f,a4=0.f,a5=0.f,a6=0.f,a7=0.f;
    if (g == 0) {               // self-loop (pad cols read zeros)
        float sc = scale2[v];
        uint2 u = *(const uint2*)(g2q + (size_t)v * 16 + lq * 2);
        a0 = fmaf(i8f(u.x,0), sc, a0); a1 = fmaf(i8f(u.x,1), sc, a1);
        a2 = fmaf(i8f(u.x,2), sc, a2); a3 = fmaf(i8f(u.x,3), sc, a3);
        a4 = fmaf(i8f(u.y,0), sc, a4); a5 = fmaf(i8f(u.y,1), sc, a5);
        a6 = fmaf(i8f(u.y,2), sc, a6); a7 = fmaf(i8f(u.y,3), sc, a7);
    }
#pragma unroll 2
    for (int k = 0; k < nk; k++) {
        int r = csr[s + k * 8];                        // pad edges -> zero row
        float sc = scale2[r];
        uint2 u = *(const uint2*)(g2q + (size_t)r * 16 + lq * 2);
        a0 = fmaf(i8f(u.x,0), sc, a0); a1 = fmaf(i8f(u.x,1), sc, a1);
        a2 = fmaf(i8f(u.x,2), sc, a2); a3 = fmaf(i8f(u.x,3), sc, a3);
        a4 = fmaf(i8f(u.y,0), sc, a4); a5 = fmaf(i8f(u.y,1), sc, a5);
        a6 = fmaf(i8f(u.y,2), sc, a6); a7 = fmaf(i8f(u.y,3), sc, a7);
    }
    // fold the 8 edge-groups
#pragma unroll
    for (int o = 8; o < 64; o <<= 1) {
        a0 += __shfl_xor(a0, o, 64); a1 += __shfl_xor(a1, o, 64);
        a2 += __shfl_xor(a2, o, 64); a3 += __shfl_xor(a3, o, 64);
        a4 += __shfl_xor(a4, o, 64); a5 += __shfl_xor(a5, o, 64);
        a6 += __shfl_xor(a6, o, 64); a7 += __shfl_xor(a7, o, 64);
    }
    float d = dinv[v];
    float4 bb0 = act ? ((const float4*)b2v)[lq * 2] : make_float4(0.f,0.f,0.f,0.f);
    float4 bb1 = act ? ((const float4*)b2v)[lq * 2 + 1] : make_float4(0.f,0.f,0.f,0.f);
    float l0 = act ? d * a0 + bb0.x : -INFINITY;
    float l1 = act ? d * a1 + bb0.y : -INFINITY;
    float l2 = act ? d * a2 + bb0.z : -INFINITY;
    float l3 = act ? d * a3 + bb0.w : -INFINITY;
    float l4 = act ? d * a4 + bb1.x : -INFINITY;
    float l5 = act ? d * a5 + bb1.y : -INFINITY;
    float l6 = act ? d * a6 + bb1.z : -INFINITY;
    float l7 = act ? d * a7 + bb1.w : -INFINITY;
    float m = fmaxf(fmaxf(fmaxf(l0, l1), fmaxf(l2, l3)),
                    fmaxf(fmaxf(l4, l5), fmaxf(l6, l7)));
#pragma unroll
    for (int o = 1; o < 8; o <<= 1) m = fmaxf(m, __shfl_xor(m, o, 64));
    float ex = act ? (__expf(l0 - m) + __expf(l1 - m) + __expf(l2 - m) +
                      __expf(l3 - m) + __expf(l4 - m) + __expf(l5 - m) +
                      __expf(l6 - m) + __expf(l7 - m)) : 0.f;
#pragma unroll
    for (int o = 1; o < 8; o <<= 1) ex += __shfl_xor(ex, o, 64);
    float lse = m + logf(ex);
    if (g == 0 && act) {
        float* op = out + (size_t)v * 40 + lq * 8;
        *(float4*)op = make_float4(l0 - lse, l1 - lse, l2 - lse, l3 - lse);
        *(float4*)(op + 4) = make_float4(l4 - lse, l5 - lse, l6 - lse, l7 - lse);
    }
}

extern "C" void kernel_launch(void* const* d_in, const int* in_sizes, int n_in,
                              void* d_out, int out_size, void* d_ws, size_t ws_size,
                              hipStream_t stream) {
    const float* x  = (const float*)d_in[0];
    const int*   ei = (const int*)d_in[1];
    const float* W1 = (const float*)d_in[2];
    const float* b1 = (const float*)d_in[3];
    const float* W2 = (const float*)d_in[4];
    const float* b2 = (const float*)d_in[5];
    float* out = (float*)d_out;

    const int N = N_NODES;
    // Workspace layout (ints from base), total ~44.6 MB:
    int*   part  = (int*)d_ws;                  // E packed partitioned edges
    int*   csr   = part + N_EDGES;              // 256*BCAP padded CSR
    int*   start = csr + NBUCK * BCAP;          // N
    int*   nkv   = start + N;                   // N  (padded deg / 8)
    int*   bcnt  = nkv + N;                     // 256*16 padded counters
    int*   fill  = bcnt + 4096;                 // 256*16 padded counters
    int*   bbase = fill + 4096;                 // 257 (+pad -> 260)
    float* dinv  = (float*)(bbase + 260);       // N
    float* scale1 = dinv + N;                   // N+1 (+pad -> N+4)
    float* scale2 = scale1 + N + 4;             // N+1 (+pad -> N+4)
    unsigned short* hb  = (unsigned short*)(scale2 + N + 4);  // N*64 bf16
    unsigned int* gb8 = (unsigned int*)(hb + (size_t)N * 64); // (N+1)*16 u32 int8 rows
    unsigned int* g2q = gb8 + (size_t)(N + 1) * 16;           // (N+1)*16 u32 int8 rows
    unsigned short* wp1 = (unsigned short*)(g2q + (size_t)(N + 1) * 16); // 4096 bf16
    unsigned short* wp2 = wp1 + 4096;                         // 3072 bf16

    k_zero<<<16, 256, 0, stream>>>(bcnt, 4096);
    k_prep<<<1, 256, 0, stream>>>(W1, W2, wp1, wp2, gb8, g2q, scale1, scale2);
    k_cnt<<<256, 256, 0, stream>>>(ei + N_EDGES, bcnt);
    k_scan256<<<1, 256, 0, stream>>>(bcnt, fill, bbase);
    k_place<<<P3_GRID, 256, 0, stream>>>(ei, fill, part);
    k_build<<<NBUCK, 256, 0, stream>>>(part, bbase, start, nkv, dinv, csr);
    k_gemm1m<<<GEMM_GRID, 256, 0, stream>>>(x, (const short8*)wp1, dinv, gb8, scale1);
    k_agg1<<<N / 4, 256, 0, stream>>>(csr, start, nkv, gb8, scale1, dinv, b1, hb);
    k_gemm2m<<<GEMM_GRID, 256, 0, stream>>>(hb, (const short8*)wp2, dinv, g2q, scale2);
    k_agg2<<<N / 4, 256, 0, stream>>>(csr, start, nkv, g2q, scale2, dinv, b2, out);
}

// Round 8
// 239.663 us; speedup vs baseline: 1.0917x; 1.0609x over previous
//
#include <hip/hip_runtime.h>
#include <hip/hip_bf16.h>
#include <math.h>

#define N_NODES 100000
#define N_EDGES 1600000
#define D_IN 64
#define D_HID 64
#define D_OUT 40
#define NBUCK 256
#define BSZ 391                 // nodes per bucket; 256*391 = 100096 >= N
#define BCAP 10240              // per-bucket capacity (mean ~6256, 50+ sd margin)
#define P3_EPB 4096             // edges per k_place block
#define P3_GRID ((N_EDGES + P3_EPB - 1) / P3_EPB)   // 391
#define GEMM_GRID ((N_NODES + 63) / 64)             // 1563 blocks, 16 nodes/wave
#define AGG_GRID (N_NODES / 8)                      // 12500 blocks, 2 nodes/wave

typedef __hip_bfloat16 bf16;
typedef __attribute__((ext_vector_type(8))) short short8;
typedef __attribute__((ext_vector_type(4))) float f32x4;

__device__ __forceinline__ float bflo(unsigned int u) {
    union { unsigned int i; float f; } c; c.i = u << 16; return c.f;
}
__device__ __forceinline__ float bfhi(unsigned int u) {
    union { unsigned int i; float f; } c; c.i = u & 0xFFFF0000u; return c.f;
}
// fp32 -> bf16 bits, round-to-nearest-even (finite inputs)
__device__ __forceinline__ unsigned short f2b(float f) {
    union { float f; unsigned int u; } c; c.f = f;
    unsigned int u = c.u + 0x7FFFu + ((c.u >> 16) & 1u);
    return (unsigned short)(u >> 16);
}
// signed byte b (0..3) of word w -> float
__device__ __forceinline__ float i8f(unsigned int w, int b) {
    return (float)((int)(w << ((3 - b) * 8)) >> 24);
}
// pack 4 quantized floats into a word
__device__ __forceinline__ unsigned int qpack(float v0, float v1, float v2,
                                              float v3, float qs) {
    int q0 = __float2int_rn(v0 * qs), q1 = __float2int_rn(v1 * qs);
    int q2 = __float2int_rn(v2 * qs), q3 = __float2int_rn(v3 * qs);
    return (unsigned int)(q0 & 255) | ((unsigned int)(q1 & 255) << 8) |
           ((unsigned int)(q2 & 255) << 16) | ((unsigned int)(q3 & 255) << 24);
}

// ---- zero ints ----
__global__ __launch_bounds__(256) void k_zero(int* __restrict__ p, int n) {
    int i = blockIdx.x * 256 + threadIdx.x;
    if (i < n) p[i] = 0;
}

// ---- place: single pass; part[] uses fixed per-bucket regions [b*BCAP ...).
// Per-block LDS count -> one global atomic per bucket -> scatter. No scan. ----
__global__ __launch_bounds__(256) void k_place(const int* __restrict__ ei,
                                               int* __restrict__ fill_p,
                                               int* __restrict__ part) {
    __shared__ int cnt_l[NBUCK];
    __shared__ int base_l[NBUCK];
    cnt_l[threadIdx.x] = 0;
    __syncthreads();
    int e0 = blockIdx.x * P3_EPB;
    unsigned int meta[16];                     // (b<<21)|(lc<<12)|slot
#pragma unroll
    for (int k = 0; k < 16; k++) {
        int e = e0 + k * 256 + threadIdx.x;
        if (e < N_EDGES) {
            unsigned int c = (unsigned int)ei[N_EDGES + e];
            unsigned int b = c / 391u;
            unsigned int lc = c - b * 391u;
            unsigned int slot = atomicAdd(&cnt_l[b], 1);   // slot < 4096
            meta[k] = (b << 21) | (lc << 12) | slot;
        } else meta[k] = 0xFFFFFFFFu;
    }
    __syncthreads();
    int cv = cnt_l[threadIdx.x];
    if (cv) base_l[threadIdx.x] = threadIdx.x * BCAP +
                                  atomicAdd(&fill_p[threadIdx.x * 16], cv);
    __syncthreads();
#pragma unroll
    for (int k = 0; k < 16; k++) {
        if (meta[k] != 0xFFFFFFFFu) {
            int e = e0 + k * 256 + threadIdx.x;
            unsigned int b = meta[k] >> 21;
            unsigned int lc = (meta[k] >> 12) & 0x1FFu;
            unsigned int slot = meta[k] & 0xFFFu;
            unsigned int r = (unsigned int)ei[e];
            part[base_l[b] + slot] = (int)((lc << 17) | r);
        }
    }
}

// ---- build: per-bucket PADDED CSR + start/nkv/dinv ----
// Node lists padded to multiple of 8 with sentinel N_NODES (zero message row).
__global__ __launch_bounds__(256) void k_build(const int* __restrict__ part,
                                               const int* __restrict__ fill_p,
                                               int* __restrict__ start,
                                               int* __restrict__ nkv,
                                               float* __restrict__ dinv,
                                               int* __restrict__ csr) {
    __shared__ int deg_l[392];
    __shared__ int excl_l[392];        // exclusive scan of PADDED degrees
    int tid = threadIdx.x;
    int b = blockIdx.x;
    int m = fill_p[b * 16];            // edges in bucket
    int base = b * BCAP;               // part & csr region base
    for (int i = tid; i < 392; i += 256) deg_l[i] = 0;
    __syncthreads();
    for (int i = tid; i < m; i += 256)
        atomicAdd(&deg_l[(unsigned int)part[base + i] >> 17], 1);
    __syncthreads();
    // wave 0: exclusive scan of padded degrees
    if (tid < 64) {
        int carry = 0;
        for (int ch = 0; ch < 7; ch++) {       // 7*64 = 448 >= 392
            int idx = ch * 64 + tid;
            int val = (idx < 392) ? ((deg_l[idx] + 7) & ~7) : 0;
            int incl = val;
#pragma unroll
            for (int off = 1; off < 64; off <<= 1) {
                int u = __shfl_up(incl, off, 64);
                if (tid >= off) incl += u;
            }
            if (idx < 392) excl_l[idx] = carry + incl - val;
            carry += __shfl(incl, 63, 64);
        }
    }
    __syncthreads();
    int v0 = b * BSZ;
    for (int vl = tid; vl < BSZ; vl += 256) {
        int v = v0 + vl;
        if (v < N_NODES) {
            int d = deg_l[vl];
            start[v] = base + excl_l[vl];
            nkv[v] = (d + 7) >> 3;
            dinv[v] = rsqrtf((float)d + 1.0f);
        }
    }
    __syncthreads();
    // fill pad slots with zero-row sentinel (uses TRUE deg, before reuse)
    for (int j = tid; j < 392 * 8; j += 256) {
        int vl = j >> 3, sl = j & 7;
        int d = deg_l[vl];
        int pc = ((d + 7) & ~7) - d;           // 0..7 pad slots
        if (sl < pc) csr[base + excl_l[vl] + d + sl] = N_NODES;
    }
    __syncthreads();
    for (int i = tid; i < 392; i += 256) deg_l[i] = 0;   // reuse as fill
    __syncthreads();
    for (int i = tid; i < m; i += 256) {
        unsigned int p = (unsigned int)part[base + i];
        unsigned int lc = p >> 17;
        int s = atomicAdd(&deg_l[lc], 1);
        csr[base + excl_l[lc] + s] = (int)(p & 0x1FFFFu);
    }
}

// ---- prep: pack W1/W2 into bf16 MFMA A-fragments; zero sentinel q-rows ----
__global__ __launch_bounds__(256) void k_prep(const float* __restrict__ W1,
                                              const float* __restrict__ W2,
                                              unsigned short* __restrict__ wp1,
                                              unsigned short* __restrict__ wp2,
                                              unsigned int* __restrict__ gb8,
                                              unsigned int* __restrict__ g2q,
                                              float* __restrict__ scale1,
                                              float* __restrict__ scale2) {
    int tid = threadIdx.x;
    if (tid < 16) gb8[(size_t)N_NODES * 16 + tid] = 0;   // sentinel zero rows
    else if (tid < 32) g2q[(size_t)N_NODES * 16 + (tid - 16)] = 0;
    else if (tid == 32) { scale1[N_NODES] = 0.f; scale2[N_NODES] = 0.f; }
    for (int i = tid; i < 4096; i += 256) {           // 2 kk * 4 jt * 64 lane * 8 e
        int e = i & 7, lane = (i >> 3) & 63, t = i >> 9;
        int kk = t >> 2, jt = t & 3;
        int row = kk * 32 + (lane >> 4) * 8 + e;
        int col = jt * 16 + (lane & 15);
        wp1[i] = f2b(W1[row * 64 + col]);
    }
    for (int i = tid; i < 3072; i += 256) {           // 2 kk * 3 jt * 64 lane * 8 e
        int e = i & 7, lane = (i >> 3) & 63, t = i >> 9;
        int kk = t / 3, jt = t - kk * 3;
        int row = kk * 32 + (lane >> 4) * 8 + e;
        int col = jt * 16 + (lane & 15);
        wp2[i] = (col < 40) ? f2b(W2[row * 40 + col]) : (unsigned short)0;
    }
}

// ---- layer1 GEMM via MFMA, int8 row-quantized output ----
__global__ __launch_bounds__(256) void k_gemm1m(const float* __restrict__ x,
                                                const short8* __restrict__ wp,
                                                const float* __restrict__ dinv,
                                                unsigned int* __restrict__ gb8,
                                                float* __restrict__ scale1) {
    int lane = threadIdx.x & 63;
    int wid = threadIdx.x >> 6;
    int node0 = (blockIdx.x * 4 + wid) * 16;
    if (node0 >= N_NODES) return;
    int vr = node0 + (lane & 15);
    if (vr >= N_NODES) vr = N_NODES - 1;               // defensive (unreachable)
    int kg = lane >> 4;
    const float* px = x + (size_t)vr * 64 + kg * 8;
    short8 b0, b1;
    {
        float4 f0 = *(const float4*)px;
        float4 f1 = *(const float4*)(px + 4);
        b0[0] = (short)f2b(f0.x); b0[1] = (short)f2b(f0.y);
        b0[2] = (short)f2b(f0.z); b0[3] = (short)f2b(f0.w);
        b0[4] = (short)f2b(f1.x); b0[5] = (short)f2b(f1.y);
        b0[6] = (short)f2b(f1.z); b0[7] = (short)f2b(f1.w);
        float4 g0 = *(const float4*)(px + 32);
        float4 g1 = *(const float4*)(px + 36);
        b1[0] = (short)f2b(g0.x); b1[1] = (short)f2b(g0.y);
        b1[2] = (short)f2b(g0.z); b1[3] = (short)f2b(g0.w);
        b1[4] = (short)f2b(g1.x); b1[5] = (short)f2b(g1.y);
        b1[6] = (short)f2b(g1.z); b1[7] = (short)f2b(g1.w);
    }
    f32x4 acc[4];
#pragma unroll
    for (int jt = 0; jt < 4; jt++) acc[jt] = (f32x4){0.f, 0.f, 0.f, 0.f};
#pragma unroll
    for (int jt = 0; jt < 4; jt++) {
        acc[jt] = __builtin_amdgcn_mfma_f32_16x16x32_bf16(
            wp[(0 * 4 + jt) * 64 + lane], b0, acc[jt], 0, 0, 0);
        acc[jt] = __builtin_amdgcn_mfma_f32_16x16x32_bf16(
            wp[(1 * 4 + jt) * 64 + lane], b1, acc[jt], 0, 0, 0);
    }
    float d = dinv[vr];
    float mv[4][4];
    float amax = 0.f;
#pragma unroll
    for (int jt = 0; jt < 4; jt++)
#pragma unroll
        for (int i = 0; i < 4; i++) {
            float val = acc[jt][i] * d;
            mv[jt][i] = val;
            amax = fmaxf(amax, fabsf(val));
        }
    amax = fmaxf(amax, __shfl_xor(amax, 16, 64));
    amax = fmaxf(amax, __shfl_xor(amax, 32, 64));
    float qs = (amax > 0.f) ? 127.f / amax : 0.f;
    if (kg == 0) scale1[vr] = amax * (1.f / 127.f);
    unsigned int* gp = gb8 + (size_t)vr * 16 + kg;
#pragma unroll
    for (int jt = 0; jt < 4; jt++)
        gp[jt * 4] = qpack(mv[jt][0], mv[jt][1], mv[jt][2], mv[jt][3], qs);
}

// ---- layer2 GEMM via MFMA, int8 row-quantized output (40 cols + zero pad) ----
__global__ __launch_bounds__(256) void k_gemm2m(const unsigned short* __restrict__ hb,
                                                const short8* __restrict__ wp,
                                                const float* __restrict__ dinv,
                                                unsigned int* __restrict__ g2q,
                                                float* __restrict__ scale2) {
    int lane = threadIdx.x & 63;
    int wid = threadIdx.x >> 6;
    int node0 = (blockIdx.x * 4 + wid) * 16;
    if (node0 >= N_NODES) return;
    int vr = node0 + (lane & 15);
    if (vr >= N_NODES) vr = N_NODES - 1;
    int kg = lane >> 4;
    const short8* h8 = (const short8*)hb;
    short8 b0 = h8[(size_t)vr * 8 + kg];
    short8 b1 = h8[(size_t)vr * 8 + 4 + kg];
    f32x4 acc[3];
#pragma unroll
    for (int jt = 0; jt < 3; jt++) acc[jt] = (f32x4){0.f, 0.f, 0.f, 0.f};
#pragma unroll
    for (int jt = 0; jt < 3; jt++) {
        acc[jt] = __builtin_amdgcn_mfma_f32_16x16x32_bf16(
            wp[(0 * 3 + jt) * 64 + lane], b0, acc[jt], 0, 0, 0);
        acc[jt] = __builtin_amdgcn_mfma_f32_16x16x32_bf16(
            wp[(1 * 3 + jt) * 64 + lane], b1, acc[jt], 0, 0, 0);
    }
    float d = dinv[vr];
    bool v2 = (kg < 2);                                // jt=2 valid only kg<2
    float mv[3][4];
    float amax = 0.f;
#pragma unroll
    for (int jt = 0; jt < 3; jt++)
#pragma unroll
        for (int i = 0; i < 4; i++) {
            float val = acc[jt][i] * d;
            mv[jt][i] = val;
            if (jt < 2 || v2) amax = fmaxf(amax, fabsf(val));
        }
    amax = fmaxf(amax, __shfl_xor(amax, 16, 64));
    amax = fmaxf(amax, __shfl_xor(amax, 32, 64));
    float qs = (amax > 0.f) ? 127.f / amax : 0.f;
    if (kg == 0) scale2[vr] = amax * (1.f / 127.f);
    unsigned int* gp = g2q + (size_t)vr * 16;
    gp[0 * 4 + kg] = qpack(mv[0][0], mv[0][1], mv[0][2], mv[0][3], qs);
    gp[1 * 4 + kg] = qpack(mv[1][0], mv[1][1], mv[1][2], mv[1][3], qs);
    gp[8 + kg] = v2 ? qpack(mv[2][0], mv[2][1], mv[2][2], mv[2][3], qs) : 0u;
    gp[12 + kg] = 0u;                                  // pad bytes 48..63
}

// ---- agg1: TWO nodes per wave (2x memory-level parallelism), 8-lane groups,
//      int8 rows + per-row scale, zero-padded csr; bias + ReLU -> hb ----
__global__ __launch_bounds__(256) void k_agg1(const int* __restrict__ csr,
                                              const int* __restrict__ start,
                                              const int* __restrict__ nkv,
                                              const unsigned int* __restrict__ gb8,
                                              const float* __restrict__ scale1,
                                              const float* __restrict__ dinv,
                                              const float* __restrict__ b1,
                                              unsigned short* __restrict__ hb) {
    int lane = threadIdx.x & 63;
    int g = lane >> 3;          // 8 edge-groups of 8 lanes
    int lq = lane & 7;          // 8B slice lq (cols 8lq..8lq+7)
    int v0 = (blockIdx.x * 4 + (threadIdx.x >> 6)) * 2;
    int v1 = v0 + 1;
    int s0 = start[v0] + g, s1 = start[v1] + g;
    int n0 = nkv[v0], n1 = nkv[v1];
    float a0=0.f,a1=0.f,a2=0.f,a3=0.f,a4=0.f,a5=0.f,a6=0.f,a7=0.f;
    float c0=0.f,c1=0.f,c2=0.f,c3=0.f,c4=0.f,c5=0.f,c6=0.f,c7=0.f;
    if (g == 0) {               // self-loops for both nodes
        float sA = scale1[v0];
        uint2 uA = *(const uint2*)(gb8 + (size_t)v0 * 16 + lq * 2);
        a0 = fmaf(i8f(uA.x,0), sA, a0); a1 = fmaf(i8f(uA.x,1), sA, a1);
        a2 = fmaf(i8f(uA.x,2), sA, a2); a3 = fmaf(i8f(uA.x,3), sA, a3);
        a4 = fmaf(i8f(uA.y,0), sA, a4); a5 = fmaf(i8f(uA.y,1), sA, a5);
        a6 = fmaf(i8f(uA.y,2), sA, a6); a7 = fmaf(i8f(uA.y,3), sA, a7);
        float sB = scale1[v1];
        uint2 uB = *(const uint2*)(gb8 + (size_t)v1 * 16 + lq * 2);
        c0 = fmaf(i8f(uB.x,0), sB, c0); c1 = fmaf(i8f(uB.x,1), sB, c1);
        c2 = fmaf(i8f(uB.x,2), sB, c2); c3 = fmaf(i8f(uB.x,3), sB, c3);
        c4 = fmaf(i8f(uB.y,0), sB, c4); c5 = fmaf(i8f(uB.y,1), sB, c5);
        c6 = fmaf(i8f(uB.y,2), sB, c6); c7 = fmaf(i8f(uB.y,3), sB, c7);
    }
    int nc = (n0 < n1) ? n0 : n1;
#pragma unroll 2
    for (int k = 0; k < nc; k++) {     // both chains in flight
        int r0 = csr[s0 + k * 8];
        int r1 = csr[s1 + k * 8];
        float sA = scale1[r0], sB = scale1[r1];
        uint2 uA = *(const uint2*)(gb8 + (size_t)r0 * 16 + lq * 2);
        uint2 uB = *(const uint2*)(gb8 + (size_t)r1 * 16 + lq * 2);
        a0 = fmaf(i8f(uA.x,0), sA, a0); a1 = fmaf(i8f(uA.x,1), sA, a1);
        a2 = fmaf(i8f(uA.x,2), sA, a2); a3 = fmaf(i8f(uA.x,3), sA, a3);
        a4 = fmaf(i8f(uA.y,0), sA, a4); a5 = fmaf(i8f(uA.y,1), sA, a5);
        a6 = fmaf(i8f(uA.y,2), sA, a6); a7 = fmaf(i8f(uA.y,3), sA, a7);
        c0 = fmaf(i8f(uB.x,0), sB, c0); c1 = fmaf(i8f(uB.x,1), sB, c1);
        c2 = fmaf(i8f(uB.x,2), sB, c2); c3 = fmaf(i8f(uB.x,3), sB, c3);
        c4 = fmaf(i8f(uB.y,0), sB, c4); c5 = fmaf(i8f(uB.y,1), sB, c5);
        c6 = fmaf(i8f(uB.y,2), sB, c6); c7 = fmaf(i8f(uB.y,3), sB, c7);
    }
    for (int k = nc; k < n0; k++) {    // tail node0 (wave-uniform)
        int r = csr[s0 + k * 8];
        float sc = scale1[r];
        uint2 u = *(const uint2*)(gb8 + (size_t)r * 16 + lq * 2);
        a0 = fmaf(i8f(u.x,0), sc, a0); a1 = fmaf(i8f(u.x,1), sc, a1);
        a2 = fmaf(i8f(u.x,2), sc, a2); a3 = fmaf(i8f(u.x,3), sc, a3);
        a4 = fmaf(i8f(u.y,0), sc, a4); a5 = fmaf(i8f(u.y,1), sc, a5);
        a6 = fmaf(i8f(u.y,2), sc, a6); a7 = fmaf(i8f(u.y,3), sc, a7);
    }
    for (int k = nc; k < n1; k++) {    // tail node1 (wave-uniform)
        int r = csr[s1 + k * 8];
        float sc = scale1[r];
        uint2 u = *(const uint2*)(gb8 + (size_t)r * 16 + lq * 2);
        c0 = fmaf(i8f(u.x,0), sc, c0); c1 = fmaf(i8f(u.x,1), sc, c1);
        c2 = fmaf(i8f(u.x,2), sc, c2); c3 = fmaf(i8f(u.x,3), sc, c3);
        c4 = fmaf(i8f(u.y,0), sc, c4); c5 = fmaf(i8f(u.y,1), sc, c5);
        c6 = fmaf(i8f(u.y,2), sc, c6); c7 = fmaf(i8f(u.y,3), sc, c7);
    }
    // fold the 8 edge-groups for both nodes (all 64 lanes active)
#pragma unroll
    for (int o = 8; o < 64; o <<= 1) {
        a0 += __shfl_xor(a0, o, 64); a1 += __shfl_xor(a1, o, 64);
        a2 += __shfl_xor(a2, o, 64); a3 += __shfl_xor(a3, o, 64);
        a4 += __shfl_xor(a4, o, 64); a5 += __shfl_xor(a5, o, 64);
        a6 += __shfl_xor(a6, o, 64); a7 += __shfl_xor(a7, o, 64);
        c0 += __shfl_xor(c0, o, 64); c1 += __shfl_xor(c1, o, 64);
        c2 += __shfl_xor(c2, o, 64); c3 += __shfl_xor(c3, o, 64);
        c4 += __shfl_xor(c4, o, 64); c5 += __shfl_xor(c5, o, 64);
        c6 += __shfl_xor(c6, o, 64); c7 += __shfl_xor(c7, o, 64);
    }
    // lanes 0-31 finish node0, lanes 32-63 finish node1
    bool hi = (lane >= 32);
    int v = hi ? v1 : v0;
    float d = dinv[v];
    float e0 = hi ? c0 : a0, e1 = hi ? c1 : a1, e2 = hi ? c2 : a2;
    float e3 = hi ? c3 : a3, e4 = hi ? c4 : a4, e5 = hi ? c5 : a5;
    float e6 = hi ? c6 : a6, e7 = hi ? c7 : a7;
    float4 bb0 = ((const float4*)b1)[lq * 2];
    float4 bb1 = ((const float4*)b1)[lq * 2 + 1];
    float h0 = fmaxf(d * e0 + bb0.x, 0.f), h1 = fmaxf(d * e1 + bb0.y, 0.f);
    float h2 = fmaxf(d * e2 + bb0.z, 0.f), h3 = fmaxf(d * e3 + bb0.w, 0.f);
    float h4 = fmaxf(d * e4 + bb1.x, 0.f), h5 = fmaxf(d * e5 + bb1.y, 0.f);
    float h6 = fmaxf(d * e6 + bb1.z, 0.f), h7 = fmaxf(d * e7 + bb1.w, 0.f);
    if (g == 0 || g == 4) {            // g==0 -> v0 (lo half), g==4 -> v1 (hi half)
        uint4 o;
        o.x = (unsigned int)f2b(h0) | ((unsigned int)f2b(h1) << 16);
        o.y = (unsigned int)f2b(h2) | ((unsigned int)f2b(h3) << 16);
        o.z = (unsigned int)f2b(h4) | ((unsigned int)f2b(h5) << 16);
        o.w = (unsigned int)f2b(h6) | ((unsigned int)f2b(h7) << 16);
        *(uint4*)(hb + (size_t)v * 64 + lq * 8) = o;
    }
}

// ---- agg2: TWO nodes per wave, int8 rows (40 cols + zero pad), per-row scale,
//      zero-padded csr; fused bias + log_softmax -> out ----
__global__ __launch_bounds__(256) void k_agg2(const int* __restrict__ csr,
                                              const int* __restrict__ start,
                                              const int* __restrict__ nkv,
                                              const unsigned int* __restrict__ g2q,
                                              const float* __restrict__ scale2,
                                              const float* __restrict__ dinv,
                                              const float* __restrict__ b2v,
                                              float* __restrict__ out) {
    int lane = threadIdx.x & 63;
    int g = lane >> 3;
    int lq = lane & 7;          // active cols at lq<5 (pad bytes read zeros)
    int v0 = (blockIdx.x * 4 + (threadIdx.x >> 6)) * 2;
    int v1 = v0 + 1;
    int s0 = start[v0] + g, s1 = start[v1] + g;
    int n0 = nkv[v0], n1 = nkv[v1];
    float a0=0.f,a1=0.f,a2=0.f,a3=0.f,a4=0.f,a5=0.f,a6=0.f,a7=0.f;
    float c0=0.f,c1=0.f,c2=0.f,c3=0.f,c4=0.f,c5=0.f,c6=0.f,c7=0.f;
    if (g == 0) {               // self-loops (pad cols read zeros)
        float sA = scale2[v0];
        uint2 uA = *(const uint2*)(g2q + (size_t)v0 * 16 + lq * 2);
        a0 = fmaf(i8f(uA.x,0), sA, a0); a1 = fmaf(i8f(uA.x,1), sA, a1);
        a2 = fmaf(i8f(uA.x,2), sA, a2); a3 = fmaf(i8f(uA.x,3), sA, a3);
        a4 = fmaf(i8f(uA.y,0), sA, a4); a5 = fmaf(i8f(uA.y,1), sA, a5);
        a6 = fmaf(i8f(uA.y,2), sA, a6); a7 = fmaf(i8f(uA.y,3), sA, a7);
        float sB = scale2[v1];
        uint2 uB = *(const uint2*)(g2q + (size_t)v1 * 16 + lq * 2);
        c0 = fmaf(i8f(uB.x,0), sB, c0); c1 = fmaf(i8f(uB.x,1), sB, c1);
        c2 = fmaf(i8f(uB.x,2), sB, c2); c3 = fmaf(i8f(uB.x,3), sB, c3);
        c4 = fmaf(i8f(uB.y,0), sB, c4); c5 = fmaf(i8f(uB.y,1), sB, c5);
        c6 = fmaf(i8f(uB.y,2), sB, c6); c7 = fmaf(i8f(uB.y,3), sB, c7);
    }
    int nc = (n0 < n1) ? n0 : n1;
#pragma unroll 2
    for (int k = 0; k < nc; k++) {
        int r0 = csr[s0 + k * 8];
        int r1 = csr[s1 + k * 8];
        float sA = scale2[r0], sB = scale2[r1];
        uint2 uA = *(const uint2*)(g2q + (size_t)r0 * 16 + lq * 2);
        uint2 uB = *(const uint2*)(g2q + (size_t)r1 * 16 + lq * 2);
        a0 = fmaf(i8f(uA.x,0), sA, a0); a1 = fmaf(i8f(uA.x,1), sA, a1);
        a2 = fmaf(i8f(uA.x,2), sA, a2); a3 = fmaf(i8f(uA.x,3), sA, a3);
        a4 = fmaf(i8f(uA.y,0), sA, a4); a5 = fmaf(i8f(uA.y,1), sA, a5);
        a6 = fmaf(i8f(uA.y,2), sA, a6); a7 = fmaf(i8f(uA.y,3), sA, a7);
        c0 = fmaf(i8f(uB.x,0), sB, c0); c1 = fmaf(i8f(uB.x,1), sB, c1);
        c2 = fmaf(i8f(uB.x,2), sB, c2); c3 = fmaf(i8f(uB.x,3), sB, c3);
        c4 = fmaf(i8f(uB.y,0), sB, c4); c5 = fmaf(i8f(uB.y,1), sB, c5);
        c6 = fmaf(i8f(uB.y,2), sB, c6); c7 = fmaf(i8f(uB.y,3), sB, c7);
    }
    for (int k = nc; k < n0; k++) {
        int r = csr[s0 + k * 8];
        float sc = scale2[r];
        uint2 u = *(const uint2*)(g2q + (size_t)r * 16 + lq * 2);
        a0 = fmaf(i8f(u.x,0), sc, a0); a1 = fmaf(i8f(u.x,1), sc, a1);
        a2 = fmaf(i8f(u.x,2), sc, a2); a3 = fmaf(i8f(u.x,3), sc, a3);
        a4 = fmaf(i8f(u.y,0), sc, a4); a5 = fmaf(i8f(u.y,1), sc, a5);
        a6 = fmaf(i8f(u.y,2), sc, a6); a7 = fmaf(i8f(u.y,3), sc, a7);
    }
    for (int k = nc; k < n1; k++) {
        int r = csr[s1 + k * 8];
        float sc = scale2[r];
        uint2 u = *(const uint2*)(g2q + (size_t)r * 16 + lq * 2);
        c0 = fmaf(i8f(u.x,0), sc, c0); c1 = fmaf(i8f(u.x,1), sc, c1);
        c2 = fmaf(i8f(u.x,2), sc, c2); c3 = fmaf(i8f(u.x,3), sc, c3);
        c4 = fmaf(i8f(u.y,0), sc, c4); c5 = fmaf(i8f(u.y,1), sc, c5);
        c6 = fmaf(i8f(u.y,2), sc, c6); c7 = fmaf(i8f(u.y,3), sc, c7);
    }
#pragma unroll
    for (int o = 8; o < 64; o <<= 1) {
        a0 += __shfl_xor(a0, o, 64); a1 += __shfl_xor(a1, o, 64);
        a2 += __shfl_xor(a2, o, 64); a3 += __shfl_xor(a3, o, 64);
        a4 += __shfl_xor(a4, o, 64); a5 += __shfl_xor(a5, o, 64);
        a6 += __shfl_xor(a6, o, 64); a7 += __shfl_xor(a7, o, 64);
        c0 += __shfl_xor(c0, o, 64); c1 += __shfl_xor(c1, o, 64);
        c2 += __shfl_xor(c2, o, 64); c3 += __shfl_xor(c3, o, 64);
        c4 += __shfl_xor(c4, o, 64); c5 += __shfl_xor(c5, o, 64);
        c6 += __shfl_xor(c6, o, 64); c7 += __shfl_xor(c7, o, 64);
    }
    // lanes 0-31 finish node0, lanes 32-63 finish node1
    bool hi = (lane >= 32);
    int v = hi ? v1 : v0;
    float d = dinv[v];
    float e0 = hi ? c0 : a0, e1 = hi ? c1 : a1, e2 = hi ? c2 : a2;
    float e3 = hi ? c3 : a3, e4 = hi ? c4 : a4, e5 = hi ? c5 : a5;
    float e6 = hi ? c6 : a6, e7 = hi ? c7 : a7;
    bool act = (lq < 5);
    float4 bb0 = act ? ((const float4*)b2v)[lq * 2] : make_float4(0.f,0.f,0.f,0.f);
    float4 bb1 = act ? ((const float4*)b2v)[lq * 2 + 1] : make_float4(0.f,0.f,0.f,0.f);
    float l0 = act ? d * e0 + bb0.x : -INFINITY;
    float l1 = act ? d * e1 + bb0.y : -INFINITY;
    float l2 = act ? d * e2 + bb0.z : -INFINITY;
    float l3 = act ? d * e3 + bb0.w : -INFINITY;
    float l4 = act ? d * e4 + bb1.x : -INFINITY;
    float l5 = act ? d * e5 + bb1.y : -INFINITY;
    float l6 = act ? d * e6 + bb1.z : -INFINITY;
    float l7 = act ? d * e7 + bb1.w : -INFINITY;
    float m = fmaxf(fmaxf(fmaxf(l0, l1), fmaxf(l2, l3)),
                    fmaxf(fmaxf(l4, l5), fmaxf(l6, l7)));
#pragma unroll
    for (int o = 1; o < 8; o <<= 1) m = fmaxf(m, __shfl_xor(m, o, 64));
    float ex = act ? (__expf(l0 - m) + __expf(l1 - m) + __expf(l2 - m) +
                      __expf(l3 - m) + __expf(l4 - m) + __expf(l5 - m) +
                      __expf(l6 - m) + __expf(l7 - m)) : 0.f;
#pragma unroll
    for (int o = 1; o < 8; o <<= 1) ex += __shfl_xor(ex, o, 64);
    float lse = m + logf(ex);
    if ((g == 0 || g == 4) && act) {   // g==0 -> v0, g==4 -> v1
        float* op = out + (size_t)v * 40 + lq * 8;
        *(float4*)op = make_float4(l0 - lse, l1 - lse, l2 - lse, l3 - lse);
        *(float4*)(op + 4) = make_float4(l4 - lse, l5 - lse, l6 - lse, l7 - lse);
    }
}

extern "C" void kernel_launch(void* const* d_in, const int* in_sizes, int n_in,
                              void* d_out, int out_size, void* d_ws, size_t ws_size,
                              hipStream_t stream) {
    const float* x  = (const float*)d_in[0];
    const int*   ei = (const int*)d_in[1];
    const float* W1 = (const float*)d_in[2];
    const float* b1 = (const float*)d_in[3];
    const float* W2 = (const float*)d_in[4];
    const float* b2 = (const float*)d_in[5];
    float* out = (float*)d_out;

    const int N = N_NODES;
    // Workspace layout (ints from base), total ~48 MB:
    int*   part  = (int*)d_ws;                  // 256*BCAP bucketized edges
    int*   csr   = part + NBUCK * BCAP;         // 256*BCAP padded CSR
    int*   start = csr + NBUCK * BCAP;          // N
    int*   nkv   = start + N;                   // N  (padded deg / 8)
    int*   fill  = nkv + N;                     // 256*16 padded counters
    float* dinv  = (float*)(fill + 4096);       // N
    float* scale1 = dinv + N;                   // N+1 (+pad -> N+4)
    float* scale2 = scale1 + N + 4;             // N+1 (+pad -> N+4)
    unsigned short* hb  = (unsigned short*)(scale2 + N + 4);  // N*64 bf16
    unsigned int* gb8 = (unsigned int*)(hb + (size_t)N * 64); // (N+1)*16 u32 int8 rows
    unsigned int* g2q = gb8 + (size_t)(N + 1) * 16;           // (N+1)*16 u32 int8 rows
    unsigned short* wp1 = (unsigned short*)(g2q + (size_t)(N + 1) * 16); // 4096 bf16
    unsigned short* wp2 = wp1 + 4096;                         // 3072 bf16

    k_zero<<<16, 256, 0, stream>>>(fill, 4096);
    k_prep<<<1, 256, 0, stream>>>(W1, W2, wp1, wp2, gb8, g2q, scale1, scale2);
    k_place<<<P3_GRID, 256, 0, stream>>>(ei, fill, part);
    k_build<<<NBUCK, 256, 0, stream>>>(part, fill, start, nkv, dinv, csr);
    k_gemm1m<<<GEMM_GRID, 256, 0, stream>>>(x, (const short8*)wp1, dinv, gb8, scale1);
    k_agg1<<<AGG_GRID, 256, 0, stream>>>(csr, start, nkv, gb8, scale1, dinv, b1, hb);
    k_gemm2m<<<GEMM_GRID, 256, 0, stream>>>(hb, (const short8*)wp2, dinv, g2q, scale2);
    k_agg2<<<AGG_GRID, 256, 0, stream>>>(csr, start, nkv, g2q, scale2, dinv, b2, out);
}

// Round 10
// 216.313 us; speedup vs baseline: 1.2096x; 1.1079x over previous
//
#include <hip/hip_runtime.h>
#include <hip/hip_bf16.h>
#include <math.h>

#define N_NODES 100000
#define N_EDGES 1600000
#define D_IN 64
#define D_HID 64
#define D_OUT 40
#define NBUCK 256
#define BSZ 391                 // nodes per bucket; 256*391 = 100096 >= N
#define BCAP 8192               // per-bucket capacity (mean ~7620 padded, 6+ sd margin)
#define P3_EPB 4096             // edges per k_place block
#define P3_GRID ((N_EDGES + P3_EPB - 1) / P3_EPB)   // 391
#define GEMM_GRID ((N_NODES + 63) / 64)             // 1563 blocks, 16 nodes/wave
#define AGG_GRID (N_NODES / 8)                      // 12500 blocks, 2 nodes/wave

typedef __hip_bfloat16 bf16;
typedef __attribute__((ext_vector_type(8))) short short8;
typedef __attribute__((ext_vector_type(4))) float f32x4;
typedef __attribute__((ext_vector_type(2))) _Float16 h2f;
typedef __attribute__((ext_vector_type(2))) __fp16 fp16x2;   // builtin return type

// fp32 -> bf16 bits, round-to-nearest-even (finite inputs)
__device__ __forceinline__ unsigned short f2b(float f) {
    union { float f; unsigned int u; } c; c.f = f;
    unsigned int u = c.u + 0x7FFFu + ((c.u >> 16) & 1u);
    return (unsigned short)(u >> 16);
}
// pack 2 fp32 -> 2 fp16 in one word
__device__ __forceinline__ unsigned int pkh(float a, float b) {
#if __has_builtin(__builtin_amdgcn_cvt_pkrtz)
    union { fp16x2 h; unsigned int u; } c;
    c.h = __builtin_amdgcn_cvt_pkrtz(a, b);
    return c.u;
#else
    union { _Float16 h[2]; unsigned int u; } c;
    c.h[0] = (_Float16)a; c.h[1] = (_Float16)b; return c.u;
#endif
}
// accumulate packed fp16 pair into two f32 accumulators (1 VALU/element via dot2)
__device__ __forceinline__ void acc2(unsigned int w, float& e, float& o) {
    union { unsigned int u; h2f h; } c; c.u = w;
#if __has_builtin(__builtin_amdgcn_fdot2)
    e = __builtin_amdgcn_fdot2(c.h, (h2f){(_Float16)1.f, (_Float16)0.f}, e, false);
    o = __builtin_amdgcn_fdot2(c.h, (h2f){(_Float16)0.f, (_Float16)1.f}, o, false);
#else
    e += (float)c.h[0]; o += (float)c.h[1];
#endif
}

// ---- zero ints ----
__global__ __launch_bounds__(256) void k_zero(int* __restrict__ p, int n) {
    int i = blockIdx.x * 256 + threadIdx.x;
    if (i < n) p[i] = 0;
}

// ---- place: single pass; part[] uses fixed per-bucket regions [b*BCAP ...).
__global__ __launch_bounds__(256) void k_place(const int* __restrict__ ei,
                                               int* __restrict__ fill_p,
                                               int* __restrict__ part) {
    __shared__ int cnt_l[NBUCK];
    __shared__ int base_l[NBUCK];
    cnt_l[threadIdx.x] = 0;
    __syncthreads();
    int e0 = blockIdx.x * P3_EPB;
    unsigned int meta[16];                     // (b<<21)|(lc<<12)|slot
#pragma unroll
    for (int k = 0; k < 16; k++) {
        int e = e0 + k * 256 + threadIdx.x;
        if (e < N_EDGES) {
            unsigned int c = (unsigned int)ei[N_EDGES + e];
            unsigned int b = c / 391u;
            unsigned int lc = c - b * 391u;
            unsigned int slot = atomicAdd(&cnt_l[b], 1);   // slot < 4096
            meta[k] = (b << 21) | (lc << 12) | slot;
        } else meta[k] = 0xFFFFFFFFu;
    }
    __syncthreads();
    int cv = cnt_l[threadIdx.x];
    if (cv) base_l[threadIdx.x] = threadIdx.x * BCAP +
                                  atomicAdd(&fill_p[threadIdx.x * 16], cv);
    __syncthreads();
#pragma unroll
    for (int k = 0; k < 16; k++) {
        if (meta[k] != 0xFFFFFFFFu) {
            int e = e0 + k * 256 + threadIdx.x;
            unsigned int b = meta[k] >> 21;
            unsigned int lc = (meta[k] >> 12) & 0x1FFu;
            unsigned int slot = meta[k] & 0xFFFu;
            unsigned int r = (unsigned int)ei[e];
            part[base_l[b] + slot] = (int)((lc << 17) | r);
        }
    }
}

// ---- build: per-bucket PADDED CSR + start/nkv/dinv ----
// Node lists padded to multiple of 8 with sentinel N_NODES (zero message row).
__global__ __launch_bounds__(256) void k_build(const int* __restrict__ part,
                                               const int* __restrict__ fill_p,
                                               int* __restrict__ start,
                                               int* __restrict__ nkv,
                                               float* __restrict__ dinv,
                                               int* __restrict__ csr) {
    __shared__ int deg_l[392];
    __shared__ int excl_l[392];        // exclusive scan of PADDED degrees
    int tid = threadIdx.x;
    int b = blockIdx.x;
    int m = fill_p[b * 16];            // edges in bucket
    int base = b * BCAP;               // part & csr region base
    for (int i = tid; i < 392; i += 256) deg_l[i] = 0;
    __syncthreads();
    for (int i = tid; i < m; i += 256)
        atomicAdd(&deg_l[(unsigned int)part[base + i] >> 17], 1);
    __syncthreads();
    // wave 0: exclusive scan of padded degrees
    if (tid < 64) {
        int carry = 0;
        for (int ch = 0; ch < 7; ch++) {       // 7*64 = 448 >= 392
            int idx = ch * 64 + tid;
            int val = (idx < 392) ? ((deg_l[idx] + 7) & ~7) : 0;
            int incl = val;
#pragma unroll
            for (int off = 1; off < 64; off <<= 1) {
                int u = __shfl_up(incl, off, 64);
                if (tid >= off) incl += u;
            }
            if (idx < 392) excl_l[idx] = carry + incl - val;
            carry += __shfl(incl, 63, 64);
        }
    }
    __syncthreads();
    int v0 = b * BSZ;
    for (int vl = tid; vl < BSZ; vl += 256) {
        int v = v0 + vl;
        if (v < N_NODES) {
            int d = deg_l[vl];
            start[v] = base + excl_l[vl];
            nkv[v] = (d + 7) >> 3;
            dinv[v] = rsqrtf((float)d + 1.0f);
        }
    }
    __syncthreads();
    // fill pad slots with zero-row sentinel (uses TRUE deg, before reuse)
    for (int j = tid; j < 392 * 8; j += 256) {
        int vl = j >> 3, sl = j & 7;
        int d = deg_l[vl];
        int pc = ((d + 7) & ~7) - d;           // 0..7 pad slots
        if (sl < pc) csr[base + excl_l[vl] + d + sl] = N_NODES;
    }
    __syncthreads();
    for (int i = tid; i < 392; i += 256) deg_l[i] = 0;   // reuse as fill
    __syncthreads();
    for (int i = tid; i < m; i += 256) {
        unsigned int p = (unsigned int)part[base + i];
        unsigned int lc = p >> 17;
        int s = atomicAdd(&deg_l[lc], 1);
        csr[base + excl_l[lc] + s] = (int)(p & 0x1FFFFu);
    }
}

// ---- prep: pack W1/W2 into bf16 MFMA A-fragments; zero sentinel fp16 rows ----
__global__ __launch_bounds__(256) void k_prep(const float* __restrict__ W1,
                                              const float* __restrict__ W2,
                                              unsigned short* __restrict__ wp1,
                                              unsigned short* __restrict__ wp2,
                                              unsigned int* __restrict__ gbh,
                                              unsigned int* __restrict__ g2h) {
    int tid = threadIdx.x;
    if (tid < 32) gbh[(size_t)N_NODES * 32 + tid] = 0;      // 128B zero row
    else if (tid < 52) g2h[(size_t)N_NODES * 20 + (tid - 32)] = 0;  // 80B zero row
    for (int i = tid; i < 4096; i += 256) {           // 2 kk * 4 jt * 64 lane * 8 e
        int e = i & 7, lane = (i >> 3) & 63, t = i >> 9;
        int kk = t >> 2, jt = t & 3;
        int row = kk * 32 + (lane >> 4) * 8 + e;
        int col = jt * 16 + (lane & 15);
        wp1[i] = f2b(W1[row * 64 + col]);
    }
    for (int i = tid; i < 3072; i += 256) {           // 2 kk * 3 jt * 64 lane * 8 e
        int e = i & 7, lane = (i >> 3) & 63, t = i >> 9;
        int kk = t / 3, jt = t - kk * 3;
        int row = kk * 32 + (lane >> 4) * 8 + e;
        int col = jt * 16 + (lane & 15);
        wp2[i] = (col < 40) ? f2b(W2[row * 40 + col]) : (unsigned short)0;
    }
}

// ---- layer1 GEMM via MFMA, fp16 row output (128B rows) ----
__global__ __launch_bounds__(256) void k_gemm1m(const float* __restrict__ x,
                                                const short8* __restrict__ wp,
                                                const float* __restrict__ dinv,
                                                unsigned short* __restrict__ gbh) {
    int lane = threadIdx.x & 63;
    int wid = threadIdx.x >> 6;
    int node0 = (blockIdx.x * 4 + wid) * 16;
    if (node0 >= N_NODES) return;
    int vr = node0 + (lane & 15);
    if (vr >= N_NODES) vr = N_NODES - 1;               // defensive (unreachable)
    int kg = lane >> 4;
    const float* px = x + (size_t)vr * 64 + kg * 8;
    short8 b0, b1;
    {
        float4 f0 = *(const float4*)px;
        float4 f1 = *(const float4*)(px + 4);
        b0[0] = (short)f2b(f0.x); b0[1] = (short)f2b(f0.y);
        b0[2] = (short)f2b(f0.z); b0[3] = (short)f2b(f0.w);
        b0[4] = (short)f2b(f1.x); b0[5] = (short)f2b(f1.y);
        b0[6] = (short)f2b(f1.z); b0[7] = (short)f2b(f1.w);
        float4 g0 = *(const float4*)(px + 32);
        float4 g1 = *(const float4*)(px + 36);
        b1[0] = (short)f2b(g0.x); b1[1] = (short)f2b(g0.y);
        b1[2] = (short)f2b(g0.z); b1[3] = (short)f2b(g0.w);
        b1[4] = (short)f2b(g1.x); b1[5] = (short)f2b(g1.y);
        b1[6] = (short)f2b(g1.z); b1[7] = (short)f2b(g1.w);
    }
    f32x4 acc[4];
#pragma unroll
    for (int jt = 0; jt < 4; jt++) acc[jt] = (f32x4){0.f, 0.f, 0.f, 0.f};
#pragma unroll
    for (int jt = 0; jt < 4; jt++) {
        acc[jt] = __builtin_amdgcn_mfma_f32_16x16x32_bf16(
            wp[(0 * 4 + jt) * 64 + lane], b0, acc[jt], 0, 0, 0);
        acc[jt] = __builtin_amdgcn_mfma_f32_16x16x32_bf16(
            wp[(1 * 4 + jt) * 64 + lane], b1, acc[jt], 0, 0, 0);
    }
    float d = dinv[vr];
    unsigned short* gp = gbh + (size_t)vr * 64 + kg * 4;
#pragma unroll
    for (int jt = 0; jt < 4; jt++) {
        uint2 w;
        w.x = pkh(acc[jt][0] * d, acc[jt][1] * d);
        w.y = pkh(acc[jt][2] * d, acc[jt][3] * d);
        *(uint2*)(gp + jt * 16) = w;
    }
}

// ---- layer2 GEMM via MFMA, fp16 row output (80B rows, 40 cols) ----
__global__ __launch_bounds__(256) void k_gemm2m(const unsigned short* __restrict__ hb,
                                                const short8* __restrict__ wp,
                                                const float* __restrict__ dinv,
                                                unsigned short* __restrict__ g2h) {
    int lane = threadIdx.x & 63;
    int wid = threadIdx.x >> 6;
    int node0 = (blockIdx.x * 4 + wid) * 16;
    if (node0 >= N_NODES) return;
    int vr = node0 + (lane & 15);
    if (vr >= N_NODES) vr = N_NODES - 1;
    int kg = lane >> 4;
    const short8* h8 = (const short8*)hb;
    short8 b0 = h8[(size_t)vr * 8 + kg];
    short8 b1 = h8[(size_t)vr * 8 + 4 + kg];
    f32x4 acc[3];
#pragma unroll
    for (int jt = 0; jt < 3; jt++) acc[jt] = (f32x4){0.f, 0.f, 0.f, 0.f};
#pragma unroll
    for (int jt = 0; jt < 3; jt++) {
        acc[jt] = __builtin_amdgcn_mfma_f32_16x16x32_bf16(
            wp[(0 * 3 + jt) * 64 + lane], b0, acc[jt], 0, 0, 0);
        acc[jt] = __builtin_amdgcn_mfma_f32_16x16x32_bf16(
            wp[(1 * 3 + jt) * 64 + lane], b1, acc[jt], 0, 0, 0);
    }
    float d = dinv[vr];
    unsigned short* gp = g2h + (size_t)vr * 40;
#pragma unroll
    for (int jt = 0; jt < 2; jt++) {
        uint2 w;
        w.x = pkh(acc[jt][0] * d, acc[jt][1] * d);
        w.y = pkh(acc[jt][2] * d, acc[jt][3] * d);
        *(uint2*)(gp + jt * 16 + kg * 4) = w;
    }
    if (kg < 2) {                                      // cols 32..39
        uint2 w;
        w.x = pkh(acc[2][0] * d, acc[2][1] * d);
        w.y = pkh(acc[2][2] * d, acc[2][3] * d);
        *(uint2*)(gp + 32 + kg * 4) = w;
    }
}

// ---- agg1: TWO nodes per wave, 8-lane groups, fp16 rows (128B), fdot2
//      accumulate (1 VALU/elem, no scales); zero-padded csr; bias+ReLU -> hb ----
__global__ __launch_bounds__(256) void k_agg1(const int* __restrict__ csr,
                                              const int* __restrict__ start,
                                              const int* __restrict__ nkv,
                                              const unsigned int* __restrict__ gbh,
                                              const float* __restrict__ dinv,
                                              const float* __restrict__ b1,
                                              unsigned short* __restrict__ hb) {
    int lane = threadIdx.x & 63;
    int g = lane >> 3;          // 8 edge-groups of 8 lanes
    int lq = lane & 7;          // 16B slice lq (cols 8lq..8lq+7)
    int v0 = (blockIdx.x * 4 + (threadIdx.x >> 6)) * 2;
    int v1 = v0 + 1;
    int s0 = start[v0] + g, s1 = start[v1] + g;
    int n0 = nkv[v0], n1 = nkv[v1];
    float a0=0.f,a1=0.f,a2=0.f,a3=0.f,a4=0.f,a5=0.f,a6=0.f,a7=0.f;
    float c0=0.f,c1=0.f,c2=0.f,c3=0.f,c4=0.f,c5=0.f,c6=0.f,c7=0.f;
    if (g == 0) {               // self-loops for both nodes
        uint4 uA = *(const uint4*)(gbh + (size_t)v0 * 32 + lq * 4);
        acc2(uA.x, a0, a1); acc2(uA.y, a2, a3);
        acc2(uA.z, a4, a5); acc2(uA.w, a6, a7);
        uint4 uB = *(const uint4*)(gbh + (size_t)v1 * 32 + lq * 4);
        acc2(uB.x, c0, c1); acc2(uB.y, c2, c3);
        acc2(uB.z, c4, c5); acc2(uB.w, c6, c7);
    }
    int nc = (n0 < n1) ? n0 : n1;
#pragma unroll 2
    for (int k = 0; k < nc; k++) {     // both chains in flight
        int r0 = csr[s0 + k * 8];
        int r1 = csr[s1 + k * 8];
        uint4 uA = *(const uint4*)(gbh + (size_t)r0 * 32 + lq * 4);
        uint4 uB = *(const uint4*)(gbh + (size_t)r1 * 32 + lq * 4);
        acc2(uA.x, a0, a1); acc2(uA.y, a2, a3);
        acc2(uA.z, a4, a5); acc2(uA.w, a6, a7);
        acc2(uB.x, c0, c1); acc2(uB.y, c2, c3);
        acc2(uB.z, c4, c5); acc2(uB.w, c6, c7);
    }
    for (int k = nc; k < n0; k++) {    // tail node0 (wave-uniform)
        int r = csr[s0 + k * 8];
        uint4 u = *(const uint4*)(gbh + (size_t)r * 32 + lq * 4);
        acc2(u.x, a0, a1); acc2(u.y, a2, a3);
        acc2(u.z, a4, a5); acc2(u.w, a6, a7);
    }
    for (int k = nc; k < n1; k++) {    // tail node1 (wave-uniform)
        int r = csr[s1 + k * 8];
        uint4 u = *(const uint4*)(gbh + (size_t)r * 32 + lq * 4);
        acc2(u.x, c0, c1); acc2(u.y, c2, c3);
        acc2(u.z, c4, c5); acc2(u.w, c6, c7);
    }
    // fold the 8 edge-groups for both nodes (all 64 lanes active)
#pragma unroll
    for (int o = 8; o < 64; o <<= 1) {
        a0 += __shfl_xor(a0, o, 64); a1 += __shfl_xor(a1, o, 64);
        a2 += __shfl_xor(a2, o, 64); a3 += __shfl_xor(a3, o, 64);
        a4 += __shfl_xor(a4, o, 64); a5 += __shfl_xor(a5, o, 64);
        a6 += __shfl_xor(a6, o, 64); a7 += __shfl_xor(a7, o, 64);
        c0 += __shfl_xor(c0, o, 64); c1 += __shfl_xor(c1, o, 64);
        c2 += __shfl_xor(c2, o, 64); c3 += __shfl_xor(c3, o, 64);
        c4 += __shfl_xor(c4, o, 64); c5 += __shfl_xor(c5, o, 64);
        c6 += __shfl_xor(c6, o, 64); c7 += __shfl_xor(c7, o, 64);
    }
    // lanes 0-31 finish node0, lanes 32-63 finish node1
    bool hi = (lane >= 32);
    int v = hi ? v1 : v0;
    float d = dinv[v];
    float e0 = hi ? c0 : a0, e1 = hi ? c1 : a1, e2 = hi ? c2 : a2;
    float e3 = hi ? c3 : a3, e4 = hi ? c4 : a4, e5 = hi ? c5 : a5;
    float e6 = hi ? c6 : a6, e7 = hi ? c7 : a7;
    float4 bb0 = ((const float4*)b1)[lq * 2];
    float4 bb1 = ((const float4*)b1)[lq * 2 + 1];
    float h0 = fmaxf(d * e0 + bb0.x, 0.f), h1 = fmaxf(d * e1 + bb0.y, 0.f);
    float h2 = fmaxf(d * e2 + bb0.z, 0.f), h3 = fmaxf(d * e3 + bb0.w, 0.f);
    float h4 = fmaxf(d * e4 + bb1.x, 0.f), h5 = fmaxf(d * e5 + bb1.y, 0.f);
    float h6 = fmaxf(d * e6 + bb1.z, 0.f), h7 = fmaxf(d * e7 + bb1.w, 0.f);
    if (g == 0 || g == 4) {            // g==0 -> v0 (lo half), g==4 -> v1 (hi half)
        uint4 o;
        o.x = (unsigned int)f2b(h0) | ((unsigned int)f2b(h1) << 16);
        o.y = (unsigned int)f2b(h2) | ((unsigned int)f2b(h3) << 16);
        o.z = (unsigned int)f2b(h4) | ((unsigned int)f2b(h5) << 16);
        o.w = (unsigned int)f2b(h6) | ((unsigned int)f2b(h7) << 16);
        *(uint4*)(hb + (size_t)v * 64 + lq * 8) = o;
    }
}

// ---- agg2: TWO nodes per wave, fp16 rows (80B, 5 active slices), fdot2;
//      zero-padded csr; fused bias + log_softmax -> out ----
__global__ __launch_bounds__(256) void k_agg2(const int* __restrict__ csr,
                                              const int* __restrict__ start,
                                              const int* __restrict__ nkv,
                                              const unsigned int* __restrict__ g2h,
                                              const float* __restrict__ dinv,
                                              const float* __restrict__ b2v,
                                              float* __restrict__ out) {
    int lane = threadIdx.x & 63;
    int g = lane >> 3;
    int lq = lane & 7;          // active slices lq<5 (5x16B = 80B row)
    int lqc = (lq < 5) ? lq : 0;   // idle lanes alias slice 0
    int v0 = (blockIdx.x * 4 + (threadIdx.x >> 6)) * 2;
    int v1 = v0 + 1;
    int s0 = start[v0] + g, s1 = start[v1] + g;
    int n0 = nkv[v0], n1 = nkv[v1];
    float a0=0.f,a1=0.f,a2=0.f,a3=0.f,a4=0.f,a5=0.f,a6=0.f,a7=0.f;
    float c0=0.f,c1=0.f,c2=0.f,c3=0.f,c4=0.f,c5=0.f,c6=0.f,c7=0.f;
    if (g == 0) {               // self-loops (idle lanes accumulate slice0 junk,
        uint4 uA = *(const uint4*)(g2h + (size_t)v0 * 20 + lqc * 4);  // masked later)
        acc2(uA.x, a0, a1); acc2(uA.y, a2, a3);
        acc2(uA.z, a4, a5); acc2(uA.w, a6, a7);
        uint4 uB = *(const uint4*)(g2h + (size_t)v1 * 20 + lqc * 4);
        acc2(uB.x, c0, c1); acc2(uB.y, c2, c3);
        acc2(uB.z, c4, c5); acc2(uB.w, c6, c7);
    }
    int nc = (n0 < n1) ? n0 : n1;
#pragma unroll 2
    for (int k = 0; k < nc; k++) {
        int r0 = csr[s0 + k * 8];
        int r1 = csr[s1 + k * 8];
        uint4 uA = *(const uint4*)(g2h + (size_t)r0 * 20 + lqc * 4);
        uint4 uB = *(const uint4*)(g2h + (size_t)r1 * 20 + lqc * 4);
        acc2(uA.x, a0, a1); acc2(uA.y, a2, a3);
        acc2(uA.z, a4, a5); acc2(uA.w, a6, a7);
        acc2(uB.x, c0, c1); acc2(uB.y, c2, c3);
        acc2(uB.z, c4, c5); acc2(uB.w, c6, c7);
    }
    for (int k = nc; k < n0; k++) {
        int r = csr[s0 + k * 8];
        uint4 u = *(const uint4*)(g2h + (size_t)r * 20 + lqc * 4);
        acc2(u.x, a0, a1); acc2(u.y, a2, a3);
        acc2(u.z, a4, a5); acc2(u.w, a6, a7);
    }
    for (int k = nc; k < n1; k++) {
        int r = csr[s1 + k * 8];
        uint4 u = *(const uint4*)(g2h + (size_t)r * 20 + lqc * 4);
        acc2(u.x, c0, c1); acc2(u.y, c2, c3);
        acc2(u.z, c4, c5); acc2(u.w, c6, c7);
    }
#pragma unroll
    for (int o = 8; o < 64; o <<= 1) {
        a0 += __shfl_xor(a0, o, 64); a1 += __shfl_xor(a1, o, 64);
        a2 += __shfl_xor(a2, o, 64); a3 += __shfl_xor(a3, o, 64);
        a4 += __shfl_xor(a4, o, 64); a5 += __shfl_xor(a5, o, 64);
        a6 += __shfl_xor(a6, o, 64); a7 += __shfl_xor(a7, o, 64);
        c0 += __shfl_xor(c0, o, 64); c1 += __shfl_xor(c1, o, 64);
        c2 += __shfl_xor(c2, o, 64); c3 += __shfl_xor(c3, o, 64);
        c4 += __shfl_xor(c4, o, 64); c5 += __shfl_xor(c5, o, 64);
        c6 += __shfl_xor(c6, o, 64); c7 += __shfl_xor(c7, o, 64);
    }
    // lanes 0-31 finish node0, lanes 32-63 finish node1
    bool hi = (lane >= 32);
    int v = hi ? v1 : v0;
    float d = dinv[v];
    float e0 = hi ? c0 : a0, e1 = hi ? c1 : a1, e2 = hi ? c2 : a2;
    float e3 = hi ? c3 : a3, e4 = hi ? c4 : a4, e5 = hi ? c5 : a5;
    float e6 = hi ? c6 : a6, e7 = hi ? c7 : a7;
    bool act = (lq < 5);
    float4 bb0 = act ? ((const float4*)b2v)[lq * 2] : make_float4(0.f,0.f,0.f,0.f);
    float4 bb1 = act ? ((const float4*)b2v)[lq * 2 + 1] : make_float4(0.f,0.f,0.f,0.f);
    float l0 = act ? d * e0 + bb0.x : -INFINITY;
    float l1 = act ? d * e1 + bb0.y : -INFINITY;
    float l2 = act ? d * e2 + bb0.z : -INFINITY;
    float l3 = act ? d * e3 + bb0.w : -INFINITY;
    float l4 = act ? d * e4 + bb1.x : -INFINITY;
    float l5 = act ? d * e5 + bb1.y : -INFINITY;
    float l6 = act ? d * e6 + bb1.z : -INFINITY;
    float l7 = act ? d * e7 + bb1.w : -INFINITY;
    float m = fmaxf(fmaxf(fmaxf(l0, l1), fmaxf(l2, l3)),
                    fmaxf(fmaxf(l4, l5), fmaxf(l6, l7)));
#pragma unroll
    for (int o = 1; o < 8; o <<= 1) m = fmaxf(m, __shfl_xor(m, o, 64));
    float ex = act ? (__expf(l0 - m) + __expf(l1 - m) + __expf(l2 - m) +
                      __expf(l3 - m) + __expf(l4 - m) + __expf(l5 - m) +
                      __expf(l6 - m) + __expf(l7 - m)) : 0.f;
#pragma unroll
    for (int o = 1; o < 8; o <<= 1) ex += __shfl_xor(ex, o, 64);
    float lse = m + logf(ex);
    if ((g == 0 || g == 4) && act) {   // g==0 -> v0, g==4 -> v1
        float* op = out + (size_t)v * 40 + lq * 8;
        *(float4*)op = make_float4(l0 - lse, l1 - lse, l2 - lse, l3 - lse);
        *(float4*)(op + 4) = make_float4(l4 - lse, l5 - lse, l6 - lse, l7 - lse);
    }
}

extern "C" void kernel_launch(void* const* d_in, const int* in_sizes, int n_in,
                              void* d_out, int out_size, void* d_ws, size_t ws_size,
                              hipStream_t stream) {
    const float* x  = (const float*)d_in[0];
    const int*   ei = (const int*)d_in[1];
    const float* W1 = (const float*)d_in[2];
    const float* b1 = (const float*)d_in[3];
    const float* W2 = (const float*)d_in[4];
    const float* b2 = (const float*)d_in[5];
    float* out = (float*)d_out;

    const int N = N_NODES;
    // Workspace layout (ints from base), total ~51 MB:
    int*   part  = (int*)d_ws;                  // 256*BCAP bucketized edges
    int*   csr   = part + NBUCK * BCAP;         // 256*BCAP padded CSR
    int*   start = csr + NBUCK * BCAP;          // N
    int*   nkv   = start + N;                   // N  (padded deg / 8)
    int*   fill  = nkv + N;                     // 256*16 padded counters
    float* dinv  = (float*)(fill + 4096);       // N
    unsigned short* hb  = (unsigned short*)(dinv + N);        // N*64 bf16
    unsigned short* gbh = hb + (size_t)N * 64;                // (N+1)*64 fp16
    unsigned short* g2h = gbh + (size_t)(N + 1) * 64;         // (N+1)*40 fp16
    unsigned short* wp1 = g2h + (size_t)(N + 1) * 40;         // 4096 bf16 W1 frags
    unsigned short* wp2 = wp1 + 4096;                         // 3072 bf16 W2 frags

    k_zero<<<16, 256, 0, stream>>>(fill, 4096);
    k_prep<<<1, 256, 0, stream>>>(W1, W2, wp1, wp2,
                                  (unsigned int*)gbh, (unsigned int*)g2h);
    k_place<<<P3_GRID, 256, 0, stream>>>(ei, fill, part);
    k_build<<<NBUCK, 256, 0, stream>>>(part, fill, start, nkv, dinv, csr);
    k_gemm1m<<<GEMM_GRID, 256, 0, stream>>>(x, (const short8*)wp1, dinv, gbh);
    k_agg1<<<AGG_GRID, 256, 0, stream>>>(csr, start, nkv, (const unsigned int*)gbh,
                                         dinv, b1, hb);
    k_gemm2m<<<GEMM_GRID, 256, 0, stream>>>(hb, (const short8*)wp2, dinv, g2h);
    k_agg2<<<AGG_GRID, 256, 0, stream>>>(csr, start, nkv, (const unsigned int*)g2h,
                                         dinv, b2, out);
}